// Round 15
// baseline (187.980 us; speedup 1.0000x reference)
//
#include <hip/hip_runtime.h>
#include <hip/hip_fp16.h>

#define F_IN 128
#define F_OUT 64
#define BSHIFT 5            // 32 nodes per bucket
#define BNODES 32
#define BCAP 1024u          // per-bucket capacity (mean fill ~512 at E=1.6M,NB=3125)
#define NBIN_BLOCKS 64      // binA grid-chunk blocks (runs of ~8 per bucket per chunk)

#define LK_A 0.505f         // leaky(v) = LK_A*v + LK_B*|v| == leaky_relu(v, 0.01)
#define LK_B 0.495f

__device__ __forceinline__ float leaky(float v) {
    return fmaf(LK_B, fabsf(v), LK_A * v);
}

template <int CTRL>
__device__ __forceinline__ float dppadd(float v) {
    return v + __builtin_bit_cast(float,
        __builtin_amdgcn_update_dpp(0, __builtin_bit_cast(int, v), CTRL, 0xf, 0xf, true));
}

// sum across each 8-lane group (pure VALU DPP); every lane gets its group's sum
__device__ __forceinline__ float sum8(float v) {
    v = dppadd<0xB1>(v);    // quad_perm [1,0,3,2]  (xor 1)
    v = dppadd<0x4E>(v);    // quad_perm [2,3,0,1]  (xor 2)
    v = dppadd<0x141>(v);   // row_half_mirror      (xor 7 within 8)
    return v;
}

// combine the 4 edge-slots of a 32-lane HALF, preserving q (lane&7)
__device__ __forceinline__ float xslot_sum2(float v) {
    v = dppadd<0x128>(v);   // row_ror:8 -> lane ^ 8 (q preserved)
    v += __shfl_xor(v, 16);
    return v;
}

// Full-wave (64-lane) sum via DPP (plan-C fallback helper)
__device__ __forceinline__ float wave_sum(float v) {
    v += __builtin_bit_cast(float, __builtin_amdgcn_update_dpp(0, __builtin_bit_cast(int, v), 0x111, 0xf, 0xf, true));
    v += __builtin_bit_cast(float, __builtin_amdgcn_update_dpp(0, __builtin_bit_cast(int, v), 0x112, 0xf, 0xf, true));
    v += __builtin_bit_cast(float, __builtin_amdgcn_update_dpp(0, __builtin_bit_cast(int, v), 0x114, 0xf, 0xe, true));
    v += __builtin_bit_cast(float, __builtin_amdgcn_update_dpp(0, __builtin_bit_cast(int, v), 0x118, 0xf, 0xc, true));
    v += __builtin_bit_cast(float, __builtin_amdgcn_update_dpp(0, __builtin_bit_cast(int, v), 0x142, 0xa, 0xf, true));
    v += __builtin_bit_cast(float, __builtin_amdgcn_update_dpp(0, __builtin_bit_cast(int, v), 0x143, 0xc, 0xf, true));
    return __builtin_bit_cast(float, __builtin_amdgcn_readlane(__builtin_bit_cast(int, v), 63));
}

__device__ __forceinline__ void cvt8(const uint4 u, float* g) {
    float2 f;
    f = __half22float2(__builtin_bit_cast(__half2, u.x)); g[0] = f.x; g[1] = f.y;
    f = __half22float2(__builtin_bit_cast(__half2, u.y)); g[2] = f.x; g[3] = f.y;
    f = __half22float2(__builtin_bit_cast(__half2, u.z)); g[4] = f.x; g[5] = f.y;
    f = __half22float2(__builtin_bit_cast(__half2, u.w)); g[6] = f.x; g[7] = f.y;
}

// ---------------- Kernel 1: fused [gemm blocks | binA blocks], 32 KB LDS ----------------
// gcur semantics: offset WITHIN bucket (memset-0 seeded).
__global__ __launch_bounds__(256) void gemm_binA(const float* __restrict__ x,
                                                 const float* __restrict__ W,
                                                 float* __restrict__ h32,
                                                 uint2* __restrict__ h16,
                                                 const int* __restrict__ ei,
                                                 unsigned* __restrict__ gcur,
                                                 unsigned* __restrict__ binned,
                                                 int N, int E, int NB, int ngemm, int nbin,
                                                 unsigned cap, int mode) {
    __shared__ unsigned smem_u[8192];   // 32 KB shared by both paths

    if ((int)blockIdx.x < ngemm) {
        // ---------- gemm path: 128 rows x 64 cols, 8 rows/thread; W fp32 in LDS ----------
        float (*w_lds)[F_OUT] = (float (*)[F_OUT])smem_u;
        {
            const float4* Wv = (const float4*)W;
            float4* wl = (float4*)w_lds;
            for (int i = threadIdx.x; i < F_IN * F_OUT / 4; i += 256) wl[i] = Wv[i];
        }
        __syncthreads();

        const int cg = threadIdx.x & 15;
        const int rs = threadIdx.x >> 4;
        const int row0 = blockIdx.x * 128 + rs * 8;

        int r[8];
#pragma unroll
        for (int i = 0; i < 8; ++i) { const int rr = row0 + i; r[i] = rr < N ? rr : N - 1; }

        float4 acc[8];
#pragma unroll
        for (int i = 0; i < 8; ++i) acc[i] = make_float4(0.f, 0.f, 0.f, 0.f);

        float4 xc[8];
#pragma unroll
        for (int i = 0; i < 8; ++i) xc[i] = *(const float4*)(x + (size_t)r[i] * F_IN);

        for (int k4 = 0; k4 < 32; ++k4) {
            float4 xn[8];
            if (k4 < 31) {
#pragma unroll
                for (int i = 0; i < 8; ++i)
                    xn[i] = *(const float4*)(x + (size_t)r[i] * F_IN + (k4 + 1) * 4);
            }
            float4 wv[4];
#pragma unroll
            for (int kk = 0; kk < 4; ++kk)
                wv[kk] = *(const float4*)&w_lds[k4 * 4 + kk][cg * 4];

#pragma unroll
            for (int i = 0; i < 8; ++i) {
                acc[i].x = fmaf(xc[i].x, wv[0].x, acc[i].x);
                acc[i].y = fmaf(xc[i].x, wv[0].y, acc[i].y);
                acc[i].z = fmaf(xc[i].x, wv[0].z, acc[i].z);
                acc[i].w = fmaf(xc[i].x, wv[0].w, acc[i].w);
                acc[i].x = fmaf(xc[i].y, wv[1].x, acc[i].x);
                acc[i].y = fmaf(xc[i].y, wv[1].y, acc[i].y);
                acc[i].z = fmaf(xc[i].y, wv[1].z, acc[i].z);
                acc[i].w = fmaf(xc[i].y, wv[1].w, acc[i].w);
                acc[i].x = fmaf(xc[i].z, wv[2].x, acc[i].x);
                acc[i].y = fmaf(xc[i].z, wv[2].y, acc[i].y);
                acc[i].z = fmaf(xc[i].z, wv[2].z, acc[i].z);
                acc[i].w = fmaf(xc[i].z, wv[2].w, acc[i].w);
                acc[i].x = fmaf(xc[i].w, wv[3].x, acc[i].x);
                acc[i].y = fmaf(xc[i].w, wv[3].y, acc[i].y);
                acc[i].z = fmaf(xc[i].w, wv[3].z, acc[i].z);
                acc[i].w = fmaf(xc[i].w, wv[3].w, acc[i].w);
            }
            if (k4 < 31) {
#pragma unroll
                for (int i = 0; i < 8; ++i) xc[i] = xn[i];
            }
        }

#pragma unroll
        for (int i = 0; i < 8; ++i) {
            const int rr = row0 + i;
            if (rr < N) {
                if (mode & 2) *(float4*)(h32 + (size_t)rr * F_OUT + cg * 4) = acc[i];
                if (mode & 1) {
                    uint2 u;
                    u.x = __builtin_bit_cast(unsigned, __floats2half2_rn(acc[i].x, acc[i].y));
                    u.y = __builtin_bit_cast(unsigned, __floats2half2_rn(acc[i].z, acc[i].w));
                    h16[(size_t)rr * 16 + cg] = u;
                }
            }
        }
    } else {
        // ---------- binA path: contiguous E/nbin chunk, two-pass (count -> reserve -> scatter) ----------
        unsigned* lcnt  = smem_u;        // [NB]
        unsigned* lbase = smem_u + NB;   // [NB]   (2*NB*4 <= 32 KB for NB<=4096)
        const int t = threadIdx.x;
        const int bi = (int)blockIdx.x - ngemm;
        const int per = (E + nbin - 1) / nbin;
        const int e0 = bi * per;
        const int e1 = min(E, e0 + per);

        for (int i = t; i < NB; i += 256) lcnt[i] = 0;
        __syncthreads();
        for (int e = e0 + t; e < e1; e += 256)
            atomicAdd(&lcnt[((unsigned)ei[e]) >> BSHIFT], 1u);
        __syncthreads();
        for (int i = t; i < NB; i += 256) {
            const unsigned c = lcnt[i];
            lbase[i] = c ? atomicAdd(&gcur[i], c) : 0u;
        }
        __syncthreads();
        for (int i = t; i < NB; i += 256) lcnt[i] = 0;   // becomes local cursor
        __syncthreads();
        for (int e = e0 + t; e < e1; e += 256) {
            const unsigned s = (unsigned)ei[e];
            const unsigned d = (unsigned)ei[E + e];
            const unsigned bk = s >> BSHIFT;
            const unsigned po = lbase[bk] + atomicAdd(&lcnt[bk], 1u);
            if (po < cap)
                binned[(size_t)bk * cap + po] = ((s & (BNODES - 1u)) << 17) | d;
        }
    }
}

// ---------------- Kernel 2: fused binB + node compute, 512 thr, one block per 32-node bucket ----------------
__global__ __launch_bounds__(512) void bucket_node(const unsigned* __restrict__ binned,
                                                   const unsigned* __restrict__ gcur,
                                                   const uint2* __restrict__ h16v,
                                                   const float* __restrict__ a,
                                                   float* __restrict__ out,
                                                   int N, unsigned cap) {
    __shared__ unsigned stg[BCAP];          // 4 KB: per-node-grouped dst indices
    __shared__ uint4    hsl[BNODES * 8];    // 4 KB: hs rows for this bucket
    __shared__ unsigned ndeg[BNODES];
    __shared__ unsigned nbase[BNODES];
    __shared__ unsigned ncur[BNODES];

    const int b = blockIdx.x;
    const int t = threadIdx.x;
    const int node0 = b << BSHIFT;
    const size_t src0 = (size_t)b * cap;
    unsigned sz = gcur[b]; if (sz > cap) sz = cap;

    if (t < BNODES) ndeg[t] = 0;
    if (t < BNODES * 8) {   // stage this bucket's hs rows (coalesced, 4 KB)
        const uint4* hsrc = (const uint4*)h16v;
        const int limit = N * 8;
        const int gi = node0 * 8 + t;
        hsl[t] = (gi < limit) ? hsrc[gi] : make_uint4(0u, 0u, 0u, 0u);
    }
    __syncthreads();

    for (unsigned i = t; i < sz; i += 512)
        atomicAdd(&ndeg[binned[src0 + i] >> 17], 1u);
    __syncthreads();

    // single-wave inclusive scan over 32 bucket-degrees
    if (t < BNODES) {
        const unsigned d = ndeg[t];
        unsigned sc = d;
#pragma unroll
        for (int st = 1; st < BNODES; st <<= 1) {
            const unsigned o = __shfl_up(sc, st, 64);
            if (t >= st) sc += o;
        }
        nbase[t] = sc - d;
        ncur[t]  = sc - d;
    }
    __syncthreads();

    for (unsigned i = t; i < sz; i += 512) {
        const unsigned p = binned[src0 + i];
        const unsigned pos = atomicAdd(&ncur[p >> 17], 1u);
        stg[pos] = p & 0x1FFFFu;
    }
    __syncthreads();

    // ---------------- node phase: 16 processors (32 lanes each), 2 nodes per processor ----------------
    const int lane  = t & 63;
    const int half  = lane >> 5;
    const int slot4 = (lane >> 3) & 3;
    const int q     = lane & 7;
    const int proc  = (t >> 6) * 2 + half;    // 0..15
    const char* h16 = (const char*)h16v;

    float b1[8], a2b[8], a3b[8], a0m[8];
#pragma unroll
    for (int f = 0; f < 8; ++f) {
        const float A0 = a[q * 8 + f];
        const float A1 = a[64 + q * 8 + f];
        const float A2 = a[128 + q * 8 + f];
        const float A3 = a[192 + q * 8 + f];
        b1[f]  = fmaf(LK_A, A2 - A3, A1);
        a2b[f] = LK_B * A2;
        a3b[f] = LK_B * A3;
        a0m[f] = fmaf(LK_A, A2 + A3, A0);
    }

#pragma unroll 1
    for (int nn = 0; nn < BNODES / 16; ++nn) {
        const int nloc = proc * (BNODES / 16) + nn;
        const int node = node0 + nloc;
        const int beg = (int)nbase[nloc];
        const int len = (int)ndeg[nloc];

        float hs[8]; cvt8(hsl[nloc * 8 + q], hs);
        float csp = 0.f;
#pragma unroll
        for (int f = 0; f < 8; ++f) csp = fmaf(hs[f], a0m[f], csp);
        const float cs = sum8(csp);

        float acc[8];
#pragma unroll
        for (int f = 0; f < 8; ++f) acc[f] = 0.f;
        float rsum = 0.f;

        const int lm1 = (len > 0) ? len - 1 : 0;
        int dA = 0;
        if (len > 0) { int e0 = slot4; if (e0 > lm1) e0 = lm1; dA = (int)stg[beg + e0]; }
        uint4 uA = *(const uint4*)(h16 + ((size_t)dA << 7) + q * 16);
        int dB = dA;
        if (len > 4) { int e1 = 4 + slot4; if (e1 > lm1) e1 = lm1; dB = (int)stg[beg + e1]; }
        uint4 uB = *(const uint4*)(h16 + ((size_t)dB << 7) + q * 16);
        int dC = dB;
        if (len > 8) { int e2 = 8 + slot4; if (e2 > lm1) e2 = lm1; dC = (int)stg[beg + e2]; }

        for (int cb = 0; cb < len; cb += 4) {
            uint4 uC = uB;
            int dD = dC;
            if (cb + 8 < len)
                uC = *(const uint4*)(h16 + ((size_t)dC << 7) + q * 16);   // 2 chunks ahead
            if (cb + 12 < len) { int e3 = cb + 12 + slot4; if (e3 > lm1) e3 = lm1; dD = (int)stg[beg + e3]; }

            float g[8];
            cvt8(uA, g);
            float p0 = 0.f, p1 = 0.f;
#pragma unroll
            for (int f = 0; f < 8; f += 2) {
                const float sa0 = hs[f] + g[f],         sb0 = hs[f] - g[f];
                const float sa1 = hs[f + 1] + g[f + 1], sb1 = hs[f + 1] - g[f + 1];
                p0 = fmaf(g[f],     b1[f],     p0);
                p1 = fmaf(g[f + 1], b1[f + 1], p1);
                p0 = fmaf(fabsf(sa0), a2b[f],     p0);
                p1 = fmaf(fabsf(sa1), a2b[f + 1], p1);
                p0 = fmaf(fabsf(sb0), a3b[f],     p0);
                p1 = fmaf(fabsf(sb1), a3b[f + 1], p1);
            }
            const float R = sum8(p0 + p1);

            float e = __expf(-leaky(cs + R));
            e = (cb + slot4 < len) ? e : 0.f;
#pragma unroll
            for (int f = 0; f < 8; ++f) acc[f] = fmaf(e, g[f], acc[f]);
            rsum += e;

            uA = uB; uB = uC; dC = dD;
        }

#pragma unroll
        for (int f = 0; f < 8; ++f) acc[f] = xslot_sum2(acc[f]);
        rsum = xslot_sum2(rsum);

        if (slot4 == 0 && node < N) {
            const float inv = 1.f / (rsum + 1e-16f);
            float4 o0, o1;
            o0.x = acc[0] * inv; o0.y = acc[1] * inv; o0.z = acc[2] * inv; o0.w = acc[3] * inv;
            o1.x = acc[4] * inv; o1.y = acc[5] * inv; o1.z = acc[6] * inv; o1.w = acc[7] * inv;
            float* orow = out + (size_t)node * F_OUT + q * 8;
            *(float4*)orow = o0;
            *(float4*)(orow + 4) = o1;
        }
    }
}

// ---------------- Plan B: old CSR build + compact node kernel ----------------
__global__ __launch_bounds__(256) void hist_kernel(const int* __restrict__ ei,
                                                   unsigned* __restrict__ cnt, int E) {
    const int e = blockIdx.x * 256 + threadIdx.x;
    if (e < E) atomicAdd(&cnt[ei[e]], 1u);
}

__global__ __launch_bounds__(256) void scan1(const unsigned* __restrict__ cnt,
                                             unsigned* __restrict__ bsum, int n) {
    __shared__ unsigned lds[256];
    const int t = threadIdx.x;
    const int base = blockIdx.x * 2048 + t * 8;
    unsigned s = 0;
#pragma unroll
    for (int i = 0; i < 8; ++i) { const int idx = base + i; if (idx < n) s += cnt[idx]; }
    lds[t] = s; __syncthreads();
    for (int st = 128; st > 0; st >>= 1) {
        if (t < st) lds[t] += lds[t + st];
        __syncthreads();
    }
    if (t == 0) bsum[blockIdx.x] = lds[0];
}

__global__ __launch_bounds__(128) void scan2(unsigned* __restrict__ bsum,
                                             unsigned* __restrict__ off, int nb, int n) {
    __shared__ unsigned lds[128];
    const int t = threadIdx.x;
    if (t < nb) lds[t] = bsum[t];
    __syncthreads();
    if (t == 0) {
        unsigned run = 0;
        for (int i = 0; i < nb; ++i) { const unsigned v = lds[i]; lds[i] = run; run += v; }
        off[n] = run;
    }
    __syncthreads();
    if (t < nb) bsum[t] = lds[t];
}

__global__ __launch_bounds__(256) void scan3(const unsigned* __restrict__ cnt,
                                             const unsigned* __restrict__ bsum,
                                             unsigned* __restrict__ off,
                                             unsigned* __restrict__ cursor, int n) {
    __shared__ unsigned lds[256];
    const int t = threadIdx.x;
    const int base = blockIdx.x * 2048 + t * 8;
    unsigned v[8]; unsigned s = 0;
#pragma unroll
    for (int i = 0; i < 8; ++i) { const int idx = base + i; v[i] = (idx < n) ? cnt[idx] : 0u; s += v[i]; }
    lds[t] = s; __syncthreads();
    for (int st = 1; st < 256; st <<= 1) {
        const unsigned add = (t >= st) ? lds[t - st] : 0u;
        __syncthreads();
        lds[t] += add;
        __syncthreads();
    }
    unsigned excl = (t > 0 ? lds[t - 1] : 0u) + bsum[blockIdx.x];
#pragma unroll
    for (int i = 0; i < 8; ++i) {
        const int idx = base + i;
        if (idx < n) { off[idx] = excl; cursor[idx] = excl; excl += v[i]; }
    }
}

__global__ __launch_bounds__(256) void scatter_kernel(const int* __restrict__ ei,
                                                      unsigned* __restrict__ cursor,
                                                      int* __restrict__ sdst, int E) {
    const int e = blockIdx.x * 256 + threadIdx.x;
    if (e >= E) return;
    const int s = ei[e];
    const int d = ei[E + e];
    const unsigned pos = atomicAdd(&cursor[s], 1u);
    sdst[pos] = d;
}

__global__ __launch_bounds__(256) void node_kernel(const unsigned* __restrict__ off,
                                                   const unsigned* __restrict__ deg,
                                                   const int* __restrict__ sdst,
                                                   const uint2* __restrict__ h16v,
                                                   const float* __restrict__ a,
                                                   float* __restrict__ out, int N) {
    const int lane  = threadIdx.x & 63;
    const int half  = lane >> 5;
    const int slot4 = (lane >> 3) & 3;
    const int q     = lane & 7;
    const char* h16 = (const char*)h16v;

    float b1[8], a2b[8], a3b[8], a0m[8];
#pragma unroll
    for (int f = 0; f < 8; ++f) {
        const float A0 = a[q * 8 + f];
        const float A1 = a[64 + q * 8 + f];
        const float A2 = a[128 + q * 8 + f];
        const float A3 = a[192 + q * 8 + f];
        b1[f]  = fmaf(LK_A, A2 - A3, A1);
        a2b[f] = LK_B * A2;
        a3b[f] = LK_B * A3;
        a0m[f] = fmaf(LK_A, A2 + A3, A0);
    }

    const int wid = (int)((blockIdx.x * 256u + threadIdx.x) >> 6);
    const int nw  = (int)((gridDim.x * 256u) >> 6);

    for (int pr = wid; pr * 2 < N; pr += nw) {
        const int node = pr * 2 + half;
        const int nc = (node < N) ? node : N - 1;
        const unsigned beg = off[nc];
        const int len = (node < N) ? (int)deg[nc] : 0;

        float hs[8];
        cvt8(*(const uint4*)(h16 + ((size_t)nc << 7) + q * 16), hs);
        float csp = 0.f;
#pragma unroll
        for (int f = 0; f < 8; ++f) csp = fmaf(hs[f], a0m[f], csp);
        const float cs = sum8(csp);

        const int lenO = __shfl_xor(len, 32);
        const int ml = (len > lenO) ? len : lenO;

        float acc[8];
#pragma unroll
        for (int f = 0; f < 8; ++f) acc[f] = 0.f;
        float rsum = 0.f;

        const int lm1 = (len > 0) ? len - 1 : 0;
        int dA = 0;
        if (len > 0) { int e0 = slot4; if (e0 > lm1) e0 = lm1; dA = sdst[beg + e0]; }
        uint4 uA = *(const uint4*)(h16 + ((size_t)dA << 7) + q * 16);
        int dB = dA;
        if (len > 4) { int e1 = 4 + slot4; if (e1 > lm1) e1 = lm1; dB = sdst[beg + e1]; }
        uint4 uB = *(const uint4*)(h16 + ((size_t)dB << 7) + q * 16);
        int dC = dB;
        if (len > 8) { int e2 = 8 + slot4; if (e2 > lm1) e2 = lm1; dC = sdst[beg + e2]; }

        for (int cb = 0; cb < ml; cb += 4) {
            uint4 uC = uB;
            int dD = dC;
            if (cb + 8 < len)
                uC = *(const uint4*)(h16 + ((size_t)dC << 7) + q * 16);
            if (cb + 12 < len) { int e3 = cb + 12 + slot4; if (e3 > lm1) e3 = lm1; dD = sdst[beg + e3]; }

            float g[8];
            cvt8(uA, g);
            float p0 = 0.f, p1 = 0.f;
#pragma unroll
            for (int f = 0; f < 8; f += 2) {
                const float sa0 = hs[f] + g[f],         sb0 = hs[f] - g[f];
                const float sa1 = hs[f + 1] + g[f + 1], sb1 = hs[f + 1] - g[f + 1];
                p0 = fmaf(g[f],     b1[f],     p0);
                p1 = fmaf(g[f + 1], b1[f + 1], p1);
                p0 = fmaf(fabsf(sa0), a2b[f],     p0);
                p1 = fmaf(fabsf(sa1), a2b[f + 1], p1);
                p0 = fmaf(fabsf(sb0), a3b[f],     p0);
                p1 = fmaf(fabsf(sb1), a3b[f + 1], p1);
            }
            const float R = sum8(p0 + p1);
            float e = __expf(-leaky(cs + R));
            e = (cb + slot4 < len) ? e : 0.f;
#pragma unroll
            for (int f = 0; f < 8; ++f) acc[f] = fmaf(e, g[f], acc[f]);
            rsum += e;
            uA = uB; uB = uC; dC = dD;
        }

#pragma unroll
        for (int f = 0; f < 8; ++f) acc[f] = xslot_sum2(acc[f]);
        rsum = xslot_sum2(rsum);

        if (slot4 == 0 && node < N) {
            const float inv = 1.f / (rsum + 1e-16f);
            float4 o0, o1;
            o0.x = acc[0] * inv; o0.y = acc[1] * inv; o0.z = acc[2] * inv; o0.w = acc[3] * inv;
            o1.x = acc[4] * inv; o1.y = acc[5] * inv; o1.z = acc[6] * inv; o1.w = acc[7] * inv;
            float* orow = out + (size_t)node * F_OUT + q * 8;
            *(float4*)orow = o0;
            *(float4*)(orow + 4) = o1;
        }
    }
}

// ---------------- Plan C: atomic fallback ----------------
__device__ __forceinline__ float edge_part(float hs, float hd, float a1, float a2, float a3) {
    float p = hd * a1;
    p = fmaf(leaky(hs + hd), a2, p);
    p = fmaf(leaky(hs - hd), a3, p);
    return p;
}

__global__ __launch_bounds__(256) void edge_kernel(const int* __restrict__ ei,
                                                   const float* __restrict__ h,
                                                   const float* __restrict__ a,
                                                   float* __restrict__ hprime,
                                                   float* __restrict__ rowsum,
                                                   int E) {
    const int lane = threadIdx.x & 63;
    const int wave = (int)((blockIdx.x * blockDim.x + threadIdx.x) >> 6);
    const int nwaves = (int)((gridDim.x * blockDim.x) >> 6);
    const float a0 = a[lane], a1 = a[64 + lane], a2 = a[128 + lane], a3 = a[192 + lane];
    for (int e = wave; e < E; e += nwaves) {
        const int s = ei[e];
        const int d = ei[E + e];
        const float hs = h[(size_t)s * F_OUT + lane];
        const float hd = h[(size_t)d * F_OUT + lane];
        const float part = wave_sum(hs * a0 + edge_part(hs, hd, a1, a2, a3));
        const float ee = __expf(-leaky(part));
        atomicAdd(&hprime[(size_t)s * F_OUT + lane], ee * hd);
        if (lane == 0) atomicAdd(&rowsum[s], ee);
    }
}

__global__ __launch_bounds__(256) void finalize(float* __restrict__ out,
                                                const float* __restrict__ rowsum,
                                                int total) {
    const int i = blockIdx.x * blockDim.x + threadIdx.x;
    if (i < total) out[i] = out[i] / (rowsum[i >> 6] + 1e-16f);
}

static inline size_t align_up(size_t v, size_t a) { return (v + a - 1) & ~(a - 1); }

extern "C" void kernel_launch(void* const* d_in, const int* in_sizes, int n_in,
                              void* d_out, int out_size, void* d_ws, size_t ws_size,
                              hipStream_t stream) {
    const float* x  = (const float*)d_in[0];
    const int*   ei = (const int*)d_in[1];
    const float* W  = (const float*)d_in[2];
    const float* a  = (const float*)d_in[3];

    const int N = in_sizes[0] / F_IN;
    const int E = in_sizes[1] / 2;
    float* out = (float*)d_out;

    const int NB = (N + BNODES - 1) >> BSHIFT;
    const int ngemm = (N + 127) / 128;
    const int nbin = NBIN_BLOCKS;
    const unsigned meanFill = (NB > 0) ? (unsigned)(E / NB) : 0u;

    char* ws = (char*)d_ws;
    const size_t szh16  = align_up((size_t)N * F_OUT * 2, 256);
    const size_t szoff  = align_up(((size_t)N + 1) * 4, 256);
    const size_t szedge = align_up((size_t)E * 4 + 64, 256);
    const size_t szbin  = align_up((size_t)NB * BCAP * 4 + 64, 256);

    // plan A: h16 | binned | gcur
    const size_t binned_b = szh16;
    const size_t gcurA_b  = binned_b + szbin;
    const size_t needA    = gcurA_b + align_up((size_t)NB * 4, 256);
    // plan B: h16 | off | deg | sdst | cursor | bsum
    const size_t offB_b   = szh16;
    const size_t degB_b   = offB_b + szoff;
    const size_t sdstB_b  = degB_b + szoff;
    const size_t cursor_b = sdstB_b + szedge;
    const size_t bsum_b   = cursor_b + align_up((size_t)N * 4, 256);
    const size_t needB    = bsum_b + 4096;

    uint2* h16 = (uint2*)ws;

    if (ws_size >= needA && N <= (1 << 17) && NB <= 4096 && meanFill <= (BCAP * 3u) / 4u) {
        unsigned* binned = (unsigned*)(ws + binned_b);
        unsigned* gcur   = (unsigned*)(ws + gcurA_b);

        hipMemsetAsync(gcur, 0, (size_t)NB * 4, stream);
        gemm_binA<<<ngemm + nbin, 256, 0, stream>>>(x, W, nullptr, h16, ei, gcur, binned,
                                                    N, E, NB, ngemm, nbin, BCAP, 1);
        bucket_node<<<NB, 512, 0, stream>>>(binned, gcur, h16, a, out, N, BCAP);
    } else if (ws_size >= needB && N <= (1 << 17)) {
        unsigned* off    = (unsigned*)(ws + offB_b);
        unsigned* deg    = (unsigned*)(ws + degB_b);
        int*      sdst   = (int*)(ws + sdstB_b);
        unsigned* cursor = (unsigned*)(ws + cursor_b);
        unsigned* bsum   = (unsigned*)(ws + bsum_b);
        const int nb2 = (N + 2047) / 2048;

        hipMemsetAsync(deg, 0, (size_t)N * 4, stream);
        gemm_binA<<<ngemm, 256, 0, stream>>>(x, W, nullptr, h16, ei, nullptr, nullptr,
                                             N, E, NB, ngemm, nbin, BCAP, 1);
        hist_kernel<<<(E + 255) / 256, 256, 0, stream>>>(ei, deg, E);
        scan1<<<nb2, 256, 0, stream>>>(deg, bsum, N);
        scan2<<<1, 128, 0, stream>>>(bsum, off, nb2, N);
        scan3<<<nb2, 256, 0, stream>>>(deg, bsum, off, cursor, N);
        scatter_kernel<<<(E + 255) / 256, 256, 0, stream>>>(ei, cursor, sdst, E);
        node_kernel<<<2048, 256, 0, stream>>>(off, deg, sdst, h16, a, out, N);
    } else {
        float* h32    = (float*)ws;
        float* rowsum = (float*)(ws + align_up((size_t)N * F_OUT * 4, 256));
        hipMemsetAsync(d_out, 0, (size_t)N * F_OUT * sizeof(float), stream);
        hipMemsetAsync(rowsum, 0, (size_t)N * sizeof(float), stream);
        gemm_binA<<<ngemm, 256, 0, stream>>>(x, W, h32, nullptr, ei, nullptr, nullptr,
                                             N, E, NB, ngemm, nbin, BCAP, 2);
        edge_kernel<<<2048, 256, 0, stream>>>(ei, h32, a, out, rowsum, E);
        finalize<<<((size_t)N * F_OUT + 255) / 256, 256, 0, stream>>>(out, rowsum, N * F_OUT);
    }
}

// Round 16
// 136.517 us; speedup vs baseline: 1.3770x; 1.3770x over previous
//
#include <hip/hip_runtime.h>
#include <hip/hip_fp16.h>

#define F_IN 128
#define F_OUT 64
#define BIN_TILE 2048
#define BSHIFT 5            // 32 nodes per bucket
#define BNODES 32
#define BCAP 1024u          // per-bucket capacity (mean fill ~512 at E=1.6M,NB=3125; 22 sigma)

#define LK_A 0.505f         // leaky(v) = LK_A*v + LK_B*|v| == leaky_relu(v, 0.01)
#define LK_B 0.495f

__device__ __forceinline__ float leaky(float v) {
    return fmaf(LK_B, fabsf(v), LK_A * v);
}

template <int CTRL>
__device__ __forceinline__ float dppadd(float v) {
    return v + __builtin_bit_cast(float,
        __builtin_amdgcn_update_dpp(0, __builtin_bit_cast(int, v), CTRL, 0xf, 0xf, true));
}

// sum across each 8-lane group (pure VALU DPP); every lane gets its group's sum
__device__ __forceinline__ float sum8(float v) {
    v = dppadd<0xB1>(v);    // quad_perm [1,0,3,2]  (xor 1)
    v = dppadd<0x4E>(v);    // quad_perm [2,3,0,1]  (xor 2)
    v = dppadd<0x141>(v);   // row_half_mirror      (xor 7 within 8)
    return v;
}

// combine the 4 edge-slots of a 32-lane HALF, preserving q (lane&7)
__device__ __forceinline__ float xslot_sum2(float v) {
    v = dppadd<0x128>(v);   // row_ror:8 -> lane ^ 8 (q preserved)
    v += __shfl_xor(v, 16);
    return v;
}

// Full-wave (64-lane) sum via DPP (plan-C fallback helper)
__device__ __forceinline__ float wave_sum(float v) {
    v += __builtin_bit_cast(float, __builtin_amdgcn_update_dpp(0, __builtin_bit_cast(int, v), 0x111, 0xf, 0xf, true));
    v += __builtin_bit_cast(float, __builtin_amdgcn_update_dpp(0, __builtin_bit_cast(int, v), 0x112, 0xf, 0xf, true));
    v += __builtin_bit_cast(float, __builtin_amdgcn_update_dpp(0, __builtin_bit_cast(int, v), 0x114, 0xf, 0xe, true));
    v += __builtin_bit_cast(float, __builtin_amdgcn_update_dpp(0, __builtin_bit_cast(int, v), 0x118, 0xf, 0xc, true));
    v += __builtin_bit_cast(float, __builtin_amdgcn_update_dpp(0, __builtin_bit_cast(int, v), 0x142, 0xa, 0xf, true));
    v += __builtin_bit_cast(float, __builtin_amdgcn_update_dpp(0, __builtin_bit_cast(int, v), 0x143, 0xc, 0xf, true));
    return __builtin_bit_cast(float, __builtin_amdgcn_readlane(__builtin_bit_cast(int, v), 63));
}

__device__ __forceinline__ void cvt8(const uint4 u, float* g) {
    float2 f;
    f = __half22float2(__builtin_bit_cast(__half2, u.x)); g[0] = f.x; g[1] = f.y;
    f = __half22float2(__builtin_bit_cast(__half2, u.y)); g[2] = f.x; g[3] = f.y;
    f = __half22float2(__builtin_bit_cast(__half2, u.z)); g[4] = f.x; g[5] = f.y;
    f = __half22float2(__builtin_bit_cast(__half2, u.w)); g[6] = f.x; g[7] = f.y;
}

// ---------------- Kernel 1: fused [gemm blocks | binA blocks], 32 KB LDS ----------------
// gcur semantics: offset WITHIN bucket (memset-0 seeded).
__global__ __launch_bounds__(256) void gemm_binA(const float* __restrict__ x,
                                                 const float* __restrict__ W,
                                                 float* __restrict__ h32,
                                                 uint2* __restrict__ h16,
                                                 const int* __restrict__ ei,
                                                 unsigned* __restrict__ gcur,
                                                 unsigned* __restrict__ binned,
                                                 int N, int E, int NB, int ngemm,
                                                 unsigned cap, int mode) {
    __shared__ unsigned smem_u[8192];   // 32 KB shared by both paths

    if ((int)blockIdx.x < ngemm) {
        // ---------- gemm path: 128 rows x 64 cols, 8 rows/thread; W fp32 in LDS ----------
        float (*w_lds)[F_OUT] = (float (*)[F_OUT])smem_u;
        {
            const float4* Wv = (const float4*)W;
            float4* wl = (float4*)w_lds;
            for (int i = threadIdx.x; i < F_IN * F_OUT / 4; i += 256) wl[i] = Wv[i];
        }
        __syncthreads();

        const int cg = threadIdx.x & 15;
        const int rs = threadIdx.x >> 4;
        const int row0 = blockIdx.x * 128 + rs * 8;

        int r[8];
#pragma unroll
        for (int i = 0; i < 8; ++i) { const int rr = row0 + i; r[i] = rr < N ? rr : N - 1; }

        float4 acc[8];
#pragma unroll
        for (int i = 0; i < 8; ++i) acc[i] = make_float4(0.f, 0.f, 0.f, 0.f);

        float4 xc[8];
#pragma unroll
        for (int i = 0; i < 8; ++i) xc[i] = *(const float4*)(x + (size_t)r[i] * F_IN);

        for (int k4 = 0; k4 < 32; ++k4) {
            float4 xn[8];
            if (k4 < 31) {
#pragma unroll
                for (int i = 0; i < 8; ++i)
                    xn[i] = *(const float4*)(x + (size_t)r[i] * F_IN + (k4 + 1) * 4);
            }
            float4 wv[4];
#pragma unroll
            for (int kk = 0; kk < 4; ++kk)
                wv[kk] = *(const float4*)&w_lds[k4 * 4 + kk][cg * 4];

#pragma unroll
            for (int i = 0; i < 8; ++i) {
                acc[i].x = fmaf(xc[i].x, wv[0].x, acc[i].x);
                acc[i].y = fmaf(xc[i].x, wv[0].y, acc[i].y);
                acc[i].z = fmaf(xc[i].x, wv[0].z, acc[i].z);
                acc[i].w = fmaf(xc[i].x, wv[0].w, acc[i].w);
                acc[i].x = fmaf(xc[i].y, wv[1].x, acc[i].x);
                acc[i].y = fmaf(xc[i].y, wv[1].y, acc[i].y);
                acc[i].z = fmaf(xc[i].y, wv[1].z, acc[i].z);
                acc[i].w = fmaf(xc[i].y, wv[1].w, acc[i].w);
                acc[i].x = fmaf(xc[i].z, wv[2].x, acc[i].x);
                acc[i].y = fmaf(xc[i].z, wv[2].y, acc[i].y);
                acc[i].z = fmaf(xc[i].z, wv[2].z, acc[i].z);
                acc[i].w = fmaf(xc[i].z, wv[2].w, acc[i].w);
                acc[i].x = fmaf(xc[i].w, wv[3].x, acc[i].x);
                acc[i].y = fmaf(xc[i].w, wv[3].y, acc[i].y);
                acc[i].z = fmaf(xc[i].w, wv[3].z, acc[i].z);
                acc[i].w = fmaf(xc[i].w, wv[3].w, acc[i].w);
            }
            if (k4 < 31) {
#pragma unroll
                for (int i = 0; i < 8; ++i) xc[i] = xn[i];
            }
        }

#pragma unroll
        for (int i = 0; i < 8; ++i) {
            const int rr = row0 + i;
            if (rr < N) {
                if (mode & 2) *(float4*)(h32 + (size_t)rr * F_OUT + cg * 4) = acc[i];
                if (mode & 1) {
                    uint2 u;
                    u.x = __builtin_bit_cast(unsigned, __floats2half2_rn(acc[i].x, acc[i].y));
                    u.y = __builtin_bit_cast(unsigned, __floats2half2_rn(acc[i].z, acc[i].w));
                    h16[(size_t)rr * 16 + cg] = u;
                }
            }
        }
    } else {
        // ---------- binA path: 2048 edges/block, bucket-local binning ----------
        unsigned* lcnt  = smem_u;        // [NB]
        unsigned* lbase = smem_u + NB;   // [NB]  (2*NB*4 <= 32 KB for NB<=4096)
        const int t = threadIdx.x;
        for (int i = t; i < NB; i += 256) lcnt[i] = 0;
        __syncthreads();
        const int base = ((int)blockIdx.x - ngemm) * BIN_TILE;
        unsigned pk[8], bk[8], rk[8];
#pragma unroll
        for (int i = 0; i < 8; ++i) {
            const int e = base + i * 256 + t;
            if (e < E) {
                const unsigned s = (unsigned)ei[e];
                const unsigned d = (unsigned)ei[E + e];
                bk[i] = s >> BSHIFT;
                pk[i] = ((s & (BNODES - 1u)) << 17) | d;
                rk[i] = atomicAdd(&lcnt[bk[i]], 1u);
            }
        }
        __syncthreads();
        for (int i = t; i < NB; i += 256) {
            const unsigned c = lcnt[i];
            lbase[i] = c ? atomicAdd(&gcur[i], c) : 0u;   // bucket-local base
        }
        __syncthreads();
#pragma unroll
        for (int i = 0; i < 8; ++i) {
            const int e = base + i * 256 + t;
            if (e < E) {
                const unsigned po = lbase[bk[i]] + rk[i];
                if (po < cap) binned[(size_t)bk[i] * cap + po] = pk[i];
            }
        }
    }
}

// ---------------- Kernel 2: fused binB + node compute, 512 thr, one block per 32-node bucket ----------------
__global__ __launch_bounds__(512) void bucket_node(const unsigned* __restrict__ binned,
                                                   const unsigned* __restrict__ gcur,
                                                   const uint2* __restrict__ h16v,
                                                   const float* __restrict__ a,
                                                   float* __restrict__ out,
                                                   int N, unsigned cap) {
    __shared__ unsigned stg[BCAP];          // 4 KB: per-node-grouped dst indices
    __shared__ uint4    hsl[BNODES * 8];    // 4 KB: hs rows for this bucket
    __shared__ unsigned ndeg[BNODES];
    __shared__ unsigned nbase[BNODES];
    __shared__ unsigned ncur[BNODES];

    const int b = blockIdx.x;
    const int t = threadIdx.x;
    const int node0 = b << BSHIFT;
    const size_t src0 = (size_t)b * cap;
    unsigned sz = gcur[b]; if (sz > cap) sz = cap;

    if (t < BNODES) ndeg[t] = 0;
    if (t < BNODES * 8) {   // stage this bucket's hs rows (coalesced, 4 KB)
        const uint4* hsrc = (const uint4*)h16v;
        const int limit = N * 8;
        const int gi = node0 * 8 + t;
        hsl[t] = (gi < limit) ? hsrc[gi] : make_uint4(0u, 0u, 0u, 0u);
    }
    __syncthreads();

    for (unsigned i = t; i < sz; i += 512)
        atomicAdd(&ndeg[binned[src0 + i] >> 17], 1u);
    __syncthreads();

    // single-wave inclusive scan over 32 bucket-degrees
    if (t < BNODES) {
        const unsigned d = ndeg[t];
        unsigned sc = d;
#pragma unroll
        for (int st = 1; st < BNODES; st <<= 1) {
            const unsigned o = __shfl_up(sc, st, 64);
            if (t >= st) sc += o;
        }
        nbase[t] = sc - d;
        ncur[t]  = sc - d;
    }
    __syncthreads();

    for (unsigned i = t; i < sz; i += 512) {
        const unsigned p = binned[src0 + i];
        const unsigned pos = atomicAdd(&ncur[p >> 17], 1u);
        stg[pos] = p & 0x1FFFFu;
    }
    __syncthreads();

    // ---------------- node phase: 16 processors (32 lanes each), 2 nodes per processor ----------------
    const int lane  = t & 63;
    const int half  = lane >> 5;
    const int slot4 = (lane >> 3) & 3;
    const int q     = lane & 7;
    const int proc  = (t >> 6) * 2 + half;    // 0..15
    const char* h16 = (const char*)h16v;

    float b1[8], a2b[8], a3b[8], a0m[8];
#pragma unroll
    for (int f = 0; f < 8; ++f) {
        const float A0 = a[q * 8 + f];
        const float A1 = a[64 + q * 8 + f];
        const float A2 = a[128 + q * 8 + f];
        const float A3 = a[192 + q * 8 + f];
        b1[f]  = fmaf(LK_A, A2 - A3, A1);
        a2b[f] = LK_B * A2;
        a3b[f] = LK_B * A3;
        a0m[f] = fmaf(LK_A, A2 + A3, A0);
    }

#pragma unroll 1
    for (int nn = 0; nn < BNODES / 16; ++nn) {
        const int nloc = proc * (BNODES / 16) + nn;
        const int node = node0 + nloc;
        const int beg = (int)nbase[nloc];
        const int len = (int)ndeg[nloc];

        float hs[8]; cvt8(hsl[nloc * 8 + q], hs);
        float csp = 0.f;
#pragma unroll
        for (int f = 0; f < 8; ++f) csp = fmaf(hs[f], a0m[f], csp);
        const float cs = sum8(csp);

        float acc[8];
#pragma unroll
        for (int f = 0; f < 8; ++f) acc[f] = 0.f;
        float rsum = 0.f;

        const int lm1 = (len > 0) ? len - 1 : 0;
        int dA = 0;
        if (len > 0) { int e0 = slot4; if (e0 > lm1) e0 = lm1; dA = (int)stg[beg + e0]; }
        uint4 uA = *(const uint4*)(h16 + ((size_t)dA << 7) + q * 16);
        int dB = dA;
        if (len > 4) { int e1 = 4 + slot4; if (e1 > lm1) e1 = lm1; dB = (int)stg[beg + e1]; }
        uint4 uB = *(const uint4*)(h16 + ((size_t)dB << 7) + q * 16);
        int dC = dB;
        if (len > 8) { int e2 = 8 + slot4; if (e2 > lm1) e2 = lm1; dC = (int)stg[beg + e2]; }

        for (int cb = 0; cb < len; cb += 4) {
            uint4 uC = uB;
            int dD = dC;
            if (cb + 8 < len)
                uC = *(const uint4*)(h16 + ((size_t)dC << 7) + q * 16);   // 2 chunks ahead
            if (cb + 12 < len) { int e3 = cb + 12 + slot4; if (e3 > lm1) e3 = lm1; dD = (int)stg[beg + e3]; }

            float g[8];
            cvt8(uA, g);
            float p0 = 0.f, p1 = 0.f;
#pragma unroll
            for (int f = 0; f < 8; f += 2) {
                const float sa0 = hs[f] + g[f],         sb0 = hs[f] - g[f];
                const float sa1 = hs[f + 1] + g[f + 1], sb1 = hs[f + 1] - g[f + 1];
                p0 = fmaf(g[f],     b1[f],     p0);
                p1 = fmaf(g[f + 1], b1[f + 1], p1);
                p0 = fmaf(fabsf(sa0), a2b[f],     p0);
                p1 = fmaf(fabsf(sa1), a2b[f + 1], p1);
                p0 = fmaf(fabsf(sb0), a3b[f],     p0);
                p1 = fmaf(fabsf(sb1), a3b[f + 1], p1);
            }
            const float R = sum8(p0 + p1);

            float e = __expf(-leaky(cs + R));
            e = (cb + slot4 < len) ? e : 0.f;
#pragma unroll
            for (int f = 0; f < 8; ++f) acc[f] = fmaf(e, g[f], acc[f]);
            rsum += e;

            uA = uB; uB = uC; dC = dD;
        }

#pragma unroll
        for (int f = 0; f < 8; ++f) acc[f] = xslot_sum2(acc[f]);
        rsum = xslot_sum2(rsum);

        if (slot4 == 0 && node < N) {
            const float inv = 1.f / (rsum + 1e-16f);
            float4 o0, o1;
            o0.x = acc[0] * inv; o0.y = acc[1] * inv; o0.z = acc[2] * inv; o0.w = acc[3] * inv;
            o1.x = acc[4] * inv; o1.y = acc[5] * inv; o1.z = acc[6] * inv; o1.w = acc[7] * inv;
            float* orow = out + (size_t)node * F_OUT + q * 8;
            *(float4*)orow = o0;
            *(float4*)(orow + 4) = o1;
        }
    }
}

// ---------------- Plan B: old CSR build + compact node kernel ----------------
__global__ __launch_bounds__(256) void hist_kernel(const int* __restrict__ ei,
                                                   unsigned* __restrict__ cnt, int E) {
    const int e = blockIdx.x * 256 + threadIdx.x;
    if (e < E) atomicAdd(&cnt[ei[e]], 1u);
}

__global__ __launch_bounds__(256) void scan1(const unsigned* __restrict__ cnt,
                                             unsigned* __restrict__ bsum, int n) {
    __shared__ unsigned lds[256];
    const int t = threadIdx.x;
    const int base = blockIdx.x * 2048 + t * 8;
    unsigned s = 0;
#pragma unroll
    for (int i = 0; i < 8; ++i) { const int idx = base + i; if (idx < n) s += cnt[idx]; }
    lds[t] = s; __syncthreads();
    for (int st = 128; st > 0; st >>= 1) {
        if (t < st) lds[t] += lds[t + st];
        __syncthreads();
    }
    if (t == 0) bsum[blockIdx.x] = lds[0];
}

__global__ __launch_bounds__(128) void scan2(unsigned* __restrict__ bsum,
                                             unsigned* __restrict__ off, int nb, int n) {
    __shared__ unsigned lds[128];
    const int t = threadIdx.x;
    if (t < nb) lds[t] = bsum[t];
    __syncthreads();
    if (t == 0) {
        unsigned run = 0;
        for (int i = 0; i < nb; ++i) { const unsigned v = lds[i]; lds[i] = run; run += v; }
        off[n] = run;
    }
    __syncthreads();
    if (t < nb) bsum[t] = lds[t];
}

__global__ __launch_bounds__(256) void scan3(const unsigned* __restrict__ cnt,
                                             const unsigned* __restrict__ bsum,
                                             unsigned* __restrict__ off,
                                             unsigned* __restrict__ cursor, int n) {
    __shared__ unsigned lds[256];
    const int t = threadIdx.x;
    const int base = blockIdx.x * 2048 + t * 8;
    unsigned v[8]; unsigned s = 0;
#pragma unroll
    for (int i = 0; i < 8; ++i) { const int idx = base + i; v[i] = (idx < n) ? cnt[idx] : 0u; s += v[i]; }
    lds[t] = s; __syncthreads();
    for (int st = 1; st < 256; st <<= 1) {
        const unsigned add = (t >= st) ? lds[t - st] : 0u;
        __syncthreads();
        lds[t] += add;
        __syncthreads();
    }
    unsigned excl = (t > 0 ? lds[t - 1] : 0u) + bsum[blockIdx.x];
#pragma unroll
    for (int i = 0; i < 8; ++i) {
        const int idx = base + i;
        if (idx < n) { off[idx] = excl; cursor[idx] = excl; excl += v[i]; }
    }
}

__global__ __launch_bounds__(256) void scatter_kernel(const int* __restrict__ ei,
                                                      unsigned* __restrict__ cursor,
                                                      int* __restrict__ sdst, int E) {
    const int e = blockIdx.x * 256 + threadIdx.x;
    if (e >= E) return;
    const int s = ei[e];
    const int d = ei[E + e];
    const unsigned pos = atomicAdd(&cursor[s], 1u);
    sdst[pos] = d;
}

__global__ __launch_bounds__(256) void node_kernel(const unsigned* __restrict__ off,
                                                   const unsigned* __restrict__ deg,
                                                   const int* __restrict__ sdst,
                                                   const uint2* __restrict__ h16v,
                                                   const float* __restrict__ a,
                                                   float* __restrict__ out, int N) {
    const int lane  = threadIdx.x & 63;
    const int half  = lane >> 5;
    const int slot4 = (lane >> 3) & 3;
    const int q     = lane & 7;
    const char* h16 = (const char*)h16v;

    float b1[8], a2b[8], a3b[8], a0m[8];
#pragma unroll
    for (int f = 0; f < 8; ++f) {
        const float A0 = a[q * 8 + f];
        const float A1 = a[64 + q * 8 + f];
        const float A2 = a[128 + q * 8 + f];
        const float A3 = a[192 + q * 8 + f];
        b1[f]  = fmaf(LK_A, A2 - A3, A1);
        a2b[f] = LK_B * A2;
        a3b[f] = LK_B * A3;
        a0m[f] = fmaf(LK_A, A2 + A3, A0);
    }

    const int wid = (int)((blockIdx.x * 256u + threadIdx.x) >> 6);
    const int nw  = (int)((gridDim.x * 256u) >> 6);

    for (int pr = wid; pr * 2 < N; pr += nw) {
        const int node = pr * 2 + half;
        const int nc = (node < N) ? node : N - 1;
        const unsigned beg = off[nc];
        const int len = (node < N) ? (int)deg[nc] : 0;

        float hs[8];
        cvt8(*(const uint4*)(h16 + ((size_t)nc << 7) + q * 16), hs);
        float csp = 0.f;
#pragma unroll
        for (int f = 0; f < 8; ++f) csp = fmaf(hs[f], a0m[f], csp);
        const float cs = sum8(csp);

        const int lenO = __shfl_xor(len, 32);
        const int ml = (len > lenO) ? len : lenO;

        float acc[8];
#pragma unroll
        for (int f = 0; f < 8; ++f) acc[f] = 0.f;
        float rsum = 0.f;

        const int lm1 = (len > 0) ? len - 1 : 0;
        int dA = 0;
        if (len > 0) { int e0 = slot4; if (e0 > lm1) e0 = lm1; dA = sdst[beg + e0]; }
        uint4 uA = *(const uint4*)(h16 + ((size_t)dA << 7) + q * 16);
        int dB = dA;
        if (len > 4) { int e1 = 4 + slot4; if (e1 > lm1) e1 = lm1; dB = sdst[beg + e1]; }
        uint4 uB = *(const uint4*)(h16 + ((size_t)dB << 7) + q * 16);
        int dC = dB;
        if (len > 8) { int e2 = 8 + slot4; if (e2 > lm1) e2 = lm1; dC = sdst[beg + e2]; }

        for (int cb = 0; cb < ml; cb += 4) {
            uint4 uC = uB;
            int dD = dC;
            if (cb + 8 < len)
                uC = *(const uint4*)(h16 + ((size_t)dC << 7) + q * 16);
            if (cb + 12 < len) { int e3 = cb + 12 + slot4; if (e3 > lm1) e3 = lm1; dD = sdst[beg + e3]; }

            float g[8];
            cvt8(uA, g);
            float p0 = 0.f, p1 = 0.f;
#pragma unroll
            for (int f = 0; f < 8; f += 2) {
                const float sa0 = hs[f] + g[f],         sb0 = hs[f] - g[f];
                const float sa1 = hs[f + 1] + g[f + 1], sb1 = hs[f + 1] - g[f + 1];
                p0 = fmaf(g[f],     b1[f],     p0);
                p1 = fmaf(g[f + 1], b1[f + 1], p1);
                p0 = fmaf(fabsf(sa0), a2b[f],     p0);
                p1 = fmaf(fabsf(sa1), a2b[f + 1], p1);
                p0 = fmaf(fabsf(sb0), a3b[f],     p0);
                p1 = fmaf(fabsf(sb1), a3b[f + 1], p1);
            }
            const float R = sum8(p0 + p1);
            float e = __expf(-leaky(cs + R));
            e = (cb + slot4 < len) ? e : 0.f;
#pragma unroll
            for (int f = 0; f < 8; ++f) acc[f] = fmaf(e, g[f], acc[f]);
            rsum += e;
            uA = uB; uB = uC; dC = dD;
        }

#pragma unroll
        for (int f = 0; f < 8; ++f) acc[f] = xslot_sum2(acc[f]);
        rsum = xslot_sum2(rsum);

        if (slot4 == 0 && node < N) {
            const float inv = 1.f / (rsum + 1e-16f);
            float4 o0, o1;
            o0.x = acc[0] * inv; o0.y = acc[1] * inv; o0.z = acc[2] * inv; o0.w = acc[3] * inv;
            o1.x = acc[4] * inv; o1.y = acc[5] * inv; o1.z = acc[6] * inv; o1.w = acc[7] * inv;
            float* orow = out + (size_t)node * F_OUT + q * 8;
            *(float4*)orow = o0;
            *(float4*)(orow + 4) = o1;
        }
    }
}

// ---------------- Plan C: atomic fallback ----------------
__device__ __forceinline__ float edge_part(float hs, float hd, float a1, float a2, float a3) {
    float p = hd * a1;
    p = fmaf(leaky(hs + hd), a2, p);
    p = fmaf(leaky(hs - hd), a3, p);
    return p;
}

__global__ __launch_bounds__(256) void edge_kernel(const int* __restrict__ ei,
                                                   const float* __restrict__ h,
                                                   const float* __restrict__ a,
                                                   float* __restrict__ hprime,
                                                   float* __restrict__ rowsum,
                                                   int E) {
    const int lane = threadIdx.x & 63;
    const int wave = (int)((blockIdx.x * blockDim.x + threadIdx.x) >> 6);
    const int nwaves = (int)((gridDim.x * blockDim.x) >> 6);
    const float a0 = a[lane], a1 = a[64 + lane], a2 = a[128 + lane], a3 = a[192 + lane];
    for (int e = wave; e < E; e += nwaves) {
        const int s = ei[e];
        const int d = ei[E + e];
        const float hs = h[(size_t)s * F_OUT + lane];
        const float hd = h[(size_t)d * F_OUT + lane];
        const float part = wave_sum(hs * a0 + edge_part(hs, hd, a1, a2, a3));
        const float ee = __expf(-leaky(part));
        atomicAdd(&hprime[(size_t)s * F_OUT + lane], ee * hd);
        if (lane == 0) atomicAdd(&rowsum[s], ee);
    }
}

__global__ __launch_bounds__(256) void finalize(float* __restrict__ out,
                                                const float* __restrict__ rowsum,
                                                int total) {
    const int i = blockIdx.x * blockDim.x + threadIdx.x;
    if (i < total) out[i] = out[i] / (rowsum[i >> 6] + 1e-16f);
}

static inline size_t align_up(size_t v, size_t a) { return (v + a - 1) & ~(a - 1); }

extern "C" void kernel_launch(void* const* d_in, const int* in_sizes, int n_in,
                              void* d_out, int out_size, void* d_ws, size_t ws_size,
                              hipStream_t stream) {
    const float* x  = (const float*)d_in[0];
    const int*   ei = (const int*)d_in[1];
    const float* W  = (const float*)d_in[2];
    const float* a  = (const float*)d_in[3];

    const int N = in_sizes[0] / F_IN;
    const int E = in_sizes[1] / 2;
    float* out = (float*)d_out;

    const int NB = (N + BNODES - 1) >> BSHIFT;
    const int ngemm = (N + 127) / 128;
    const int nbt = (E + BIN_TILE - 1) / BIN_TILE;
    const unsigned meanFill = (NB > 0) ? (unsigned)(E / NB) : 0u;

    char* ws = (char*)d_ws;
    const size_t szh16  = align_up((size_t)N * F_OUT * 2, 256);
    const size_t szoff  = align_up(((size_t)N + 1) * 4, 256);
    const size_t szedge = align_up((size_t)E * 4 + 64, 256);
    const size_t szbin  = align_up((size_t)NB * BCAP * 4 + 64, 256);

    // plan A: h16 | binned | gcur
    const size_t binned_b = szh16;
    const size_t gcurA_b  = binned_b + szbin;
    const size_t needA    = gcurA_b + align_up((size_t)NB * 4, 256);
    // plan B: h16 | off | deg | sdst | cursor | bsum
    const size_t offB_b   = szh16;
    const size_t degB_b   = offB_b + szoff;
    const size_t sdstB_b  = degB_b + szoff;
    const size_t cursor_b = sdstB_b + szedge;
    const size_t bsum_b   = cursor_b + align_up((size_t)N * 4, 256);
    const size_t needB    = bsum_b + 4096;

    uint2* h16 = (uint2*)ws;

    if (ws_size >= needA && N <= (1 << 17) && NB <= 4096 && meanFill <= (BCAP * 3u) / 4u) {
        unsigned* binned = (unsigned*)(ws + binned_b);
        unsigned* gcur   = (unsigned*)(ws + gcurA_b);

        hipMemsetAsync(gcur, 0, (size_t)NB * 4, stream);
        gemm_binA<<<ngemm + nbt, 256, 0, stream>>>(x, W, nullptr, h16, ei, gcur, binned,
                                                   N, E, NB, ngemm, BCAP, 1);
        bucket_node<<<NB, 512, 0, stream>>>(binned, gcur, h16, a, out, N, BCAP);
    } else if (ws_size >= needB && N <= (1 << 17)) {
        unsigned* off    = (unsigned*)(ws + offB_b);
        unsigned* deg    = (unsigned*)(ws + degB_b);
        int*      sdst   = (int*)(ws + sdstB_b);
        unsigned* cursor = (unsigned*)(ws + cursor_b);
        unsigned* bsum   = (unsigned*)(ws + bsum_b);
        const int nb2 = (N + 2047) / 2048;

        hipMemsetAsync(deg, 0, (size_t)N * 4, stream);
        gemm_binA<<<ngemm, 256, 0, stream>>>(x, W, nullptr, h16, ei, nullptr, nullptr,
                                             N, E, NB, ngemm, BCAP, 1);
        hist_kernel<<<(E + 255) / 256, 256, 0, stream>>>(ei, deg, E);
        scan1<<<nb2, 256, 0, stream>>>(deg, bsum, N);
        scan2<<<1, 128, 0, stream>>>(bsum, off, nb2, N);
        scan3<<<nb2, 256, 0, stream>>>(deg, bsum, off, cursor, N);
        scatter_kernel<<<(E + 255) / 256, 256, 0, stream>>>(ei, cursor, sdst, E);
        node_kernel<<<2048, 256, 0, stream>>>(off, deg, sdst, h16, a, out, N);
    } else {
        float* h32    = (float*)ws;
        float* rowsum = (float*)(ws + align_up((size_t)N * F_OUT * 4, 256));
        hipMemsetAsync(d_out, 0, (size_t)N * F_OUT * sizeof(float), stream);
        hipMemsetAsync(rowsum, 0, (size_t)N * sizeof(float), stream);
        gemm_binA<<<ngemm, 256, 0, stream>>>(x, W, h32, nullptr, ei, nullptr, nullptr,
                                             N, E, NB, ngemm, BCAP, 2);
        edge_kernel<<<2048, 256, 0, stream>>>(ei, h32, a, out, rowsum, E);
        finalize<<<((size_t)N * F_OUT + 255) / 256, 256, 0, stream>>>(out, rowsum, N * F_OUT);
    }
}

// Round 17
// 131.309 us; speedup vs baseline: 1.4316x; 1.0397x over previous
//
#include <hip/hip_runtime.h>
#include <hip/hip_fp16.h>

#define F_IN 128
#define F_OUT 64
#define BIN_TILE 2048
#define BSHIFT 6            // 64 nodes per bucket
#define BNODES 64
#define BCAP 2048u          // per-bucket capacity (mean fill ~1024 at E=1.6M,NB=1563)

#define LK_A 0.505f         // leaky(v) = LK_A*v + LK_B*|v| == leaky_relu(v, 0.01)
#define LK_B 0.495f

__device__ __forceinline__ float leaky(float v) {
    return fmaf(LK_B, fabsf(v), LK_A * v);
}

template <int CTRL>
__device__ __forceinline__ float dppadd(float v) {
    return v + __builtin_bit_cast(float,
        __builtin_amdgcn_update_dpp(0, __builtin_bit_cast(int, v), CTRL, 0xf, 0xf, true));
}

// sum across each 8-lane group (pure VALU DPP); every lane gets its group's sum
__device__ __forceinline__ float sum8(float v) {
    v = dppadd<0xB1>(v);    // quad_perm [1,0,3,2]  (xor 1)
    v = dppadd<0x4E>(v);    // quad_perm [2,3,0,1]  (xor 2)
    v = dppadd<0x141>(v);   // row_half_mirror      (xor 7 within 8)
    return v;
}

// combine the 4 edge-slots of a 32-lane HALF, preserving q (lane&7)
__device__ __forceinline__ float xslot_sum2(float v) {
    v = dppadd<0x128>(v);   // row_ror:8 -> lane ^ 8 (q preserved)
    v += __shfl_xor(v, 16);
    return v;
}

// Full-wave (64-lane) sum via DPP (plan-C fallback helper)
__device__ __forceinline__ float wave_sum(float v) {
    v += __builtin_bit_cast(float, __builtin_amdgcn_update_dpp(0, __builtin_bit_cast(int, v), 0x111, 0xf, 0xf, true));
    v += __builtin_bit_cast(float, __builtin_amdgcn_update_dpp(0, __builtin_bit_cast(int, v), 0x112, 0xf, 0xf, true));
    v += __builtin_bit_cast(float, __builtin_amdgcn_update_dpp(0, __builtin_bit_cast(int, v), 0x114, 0xf, 0xe, true));
    v += __builtin_bit_cast(float, __builtin_amdgcn_update_dpp(0, __builtin_bit_cast(int, v), 0x118, 0xf, 0xc, true));
    v += __builtin_bit_cast(float, __builtin_amdgcn_update_dpp(0, __builtin_bit_cast(int, v), 0x142, 0xa, 0xf, true));
    v += __builtin_bit_cast(float, __builtin_amdgcn_update_dpp(0, __builtin_bit_cast(int, v), 0x143, 0xc, 0xf, true));
    return __builtin_bit_cast(float, __builtin_amdgcn_readlane(__builtin_bit_cast(int, v), 63));
}

__device__ __forceinline__ void cvt8(const uint4 u, float* g) {
    float2 f;
    f = __half22float2(__builtin_bit_cast(__half2, u.x)); g[0] = f.x; g[1] = f.y;
    f = __half22float2(__builtin_bit_cast(__half2, u.y)); g[2] = f.x; g[3] = f.y;
    f = __half22float2(__builtin_bit_cast(__half2, u.z)); g[4] = f.x; g[5] = f.y;
    f = __half22float2(__builtin_bit_cast(__half2, u.w)); g[6] = f.x; g[7] = f.y;
}

// ---------------- Kernel 1: fused [gemm blocks | binA blocks], 32 KB LDS ----------------
// gcur semantics: offset WITHIN bucket (memset-0 seeded).
__global__ __launch_bounds__(256) void gemm_binA(const float* __restrict__ x,
                                                 const float* __restrict__ W,
                                                 float* __restrict__ h32,
                                                 uint2* __restrict__ h16,
                                                 const int* __restrict__ ei,
                                                 unsigned* __restrict__ gcur,
                                                 unsigned* __restrict__ binned,
                                                 int N, int E, int NB, int ngemm,
                                                 unsigned cap, int mode) {
    __shared__ unsigned smem_u[8192];   // 32 KB shared by both paths

    if ((int)blockIdx.x < ngemm) {
        // ---------- gemm path: 128 rows x 64 cols, 8 rows/thread; W fp32 in LDS ----------
        float (*w_lds)[F_OUT] = (float (*)[F_OUT])smem_u;
        {
            const float4* Wv = (const float4*)W;
            float4* wl = (float4*)w_lds;
            for (int i = threadIdx.x; i < F_IN * F_OUT / 4; i += 256) wl[i] = Wv[i];
        }
        __syncthreads();

        const int cg = threadIdx.x & 15;
        const int rs = threadIdx.x >> 4;
        const int row0 = blockIdx.x * 128 + rs * 8;

        int r[8];
#pragma unroll
        for (int i = 0; i < 8; ++i) { const int rr = row0 + i; r[i] = rr < N ? rr : N - 1; }

        float4 acc[8];
#pragma unroll
        for (int i = 0; i < 8; ++i) acc[i] = make_float4(0.f, 0.f, 0.f, 0.f);

        float4 xc[8];
#pragma unroll
        for (int i = 0; i < 8; ++i) xc[i] = *(const float4*)(x + (size_t)r[i] * F_IN);

        for (int k4 = 0; k4 < 32; ++k4) {
            float4 xn[8];
            if (k4 < 31) {
#pragma unroll
                for (int i = 0; i < 8; ++i)
                    xn[i] = *(const float4*)(x + (size_t)r[i] * F_IN + (k4 + 1) * 4);
            }
            float4 wv[4];
#pragma unroll
            for (int kk = 0; kk < 4; ++kk)
                wv[kk] = *(const float4*)&w_lds[k4 * 4 + kk][cg * 4];

#pragma unroll
            for (int i = 0; i < 8; ++i) {
                acc[i].x = fmaf(xc[i].x, wv[0].x, acc[i].x);
                acc[i].y = fmaf(xc[i].x, wv[0].y, acc[i].y);
                acc[i].z = fmaf(xc[i].x, wv[0].z, acc[i].z);
                acc[i].w = fmaf(xc[i].x, wv[0].w, acc[i].w);
                acc[i].x = fmaf(xc[i].y, wv[1].x, acc[i].x);
                acc[i].y = fmaf(xc[i].y, wv[1].y, acc[i].y);
                acc[i].z = fmaf(xc[i].y, wv[1].z, acc[i].z);
                acc[i].w = fmaf(xc[i].y, wv[1].w, acc[i].w);
                acc[i].x = fmaf(xc[i].z, wv[2].x, acc[i].x);
                acc[i].y = fmaf(xc[i].z, wv[2].y, acc[i].y);
                acc[i].z = fmaf(xc[i].z, wv[2].z, acc[i].z);
                acc[i].w = fmaf(xc[i].z, wv[2].w, acc[i].w);
                acc[i].x = fmaf(xc[i].w, wv[3].x, acc[i].x);
                acc[i].y = fmaf(xc[i].w, wv[3].y, acc[i].y);
                acc[i].z = fmaf(xc[i].w, wv[3].z, acc[i].z);
                acc[i].w = fmaf(xc[i].w, wv[3].w, acc[i].w);
            }
            if (k4 < 31) {
#pragma unroll
                for (int i = 0; i < 8; ++i) xc[i] = xn[i];
            }
        }

#pragma unroll
        for (int i = 0; i < 8; ++i) {
            const int rr = row0 + i;
            if (rr < N) {
                if (mode & 2) *(float4*)(h32 + (size_t)rr * F_OUT + cg * 4) = acc[i];
                if (mode & 1) {
                    uint2 u;
                    u.x = __builtin_bit_cast(unsigned, __floats2half2_rn(acc[i].x, acc[i].y));
                    u.y = __builtin_bit_cast(unsigned, __floats2half2_rn(acc[i].z, acc[i].w));
                    h16[(size_t)rr * 16 + cg] = u;
                }
            }
        }
    } else {
        // ---------- binA path: 2048 edges/block, bucket-local binning ----------
        unsigned* lcnt  = smem_u;        // [NB]
        unsigned* lbase = smem_u + NB;   // [NB]  (2*NB*4 <= 32 KB for NB<=4096)
        const int t = threadIdx.x;
        for (int i = t; i < NB; i += 256) lcnt[i] = 0;
        __syncthreads();
        const int base = ((int)blockIdx.x - ngemm) * BIN_TILE;
        unsigned pk[8], bk[8], rk[8];
#pragma unroll
        for (int i = 0; i < 8; ++i) {
            const int e = base + i * 256 + t;
            if (e < E) {
                const unsigned s = (unsigned)ei[e];
                const unsigned d = (unsigned)ei[E + e];
                bk[i] = s >> BSHIFT;
                pk[i] = ((s & (BNODES - 1u)) << 17) | d;
                rk[i] = atomicAdd(&lcnt[bk[i]], 1u);
            }
        }
        __syncthreads();
        for (int i = t; i < NB; i += 256) {
            const unsigned c = lcnt[i];
            lbase[i] = c ? atomicAdd(&gcur[i], c) : 0u;   // bucket-local base
        }
        __syncthreads();
#pragma unroll
        for (int i = 0; i < 8; ++i) {
            const int e = base + i * 256 + t;
            if (e < E) {
                const unsigned po = lbase[bk[i]] + rk[i];
                if (po < cap) binned[(size_t)bk[i] * cap + po] = pk[i];
            }
        }
    }
}

// ---------------- Kernel 2: fused binB + node compute, 512 thr, one block per 64-node bucket ----------------
// Single global pass over binned: raw edges staged in LDS; hist/scan/scatter from LDS.
__global__ __launch_bounds__(512) void bucket_node(const unsigned* __restrict__ binned,
                                                   const unsigned* __restrict__ gcur,
                                                   const uint2* __restrict__ h16v,
                                                   const float* __restrict__ a,
                                                   float* __restrict__ out,
                                                   int N, unsigned cap) {
    __shared__ unsigned raw[BCAP];          // 8 KB: raw (ungrouped) payloads
    __shared__ unsigned stg[BCAP];          // 8 KB: per-node-grouped dst indices
    __shared__ uint4    hsl[BNODES * 8];    // 8 KB: hs rows for this bucket
    __shared__ unsigned ndeg[BNODES];
    __shared__ unsigned nbase[BNODES];
    __shared__ unsigned ncur[BNODES];

    const int b = blockIdx.x;
    const int t = threadIdx.x;
    const int node0 = b << BSHIFT;
    const size_t src0 = (size_t)b * cap;
    unsigned sz = gcur[b]; if (sz > cap) sz = cap;

    if (t < BNODES) ndeg[t] = 0;
    {   // stage this bucket's hs rows (coalesced, 8 KB: one uint4 per thread)
        const uint4* hsrc = (const uint4*)h16v;
        const int limit = N * 8;
        const int gi = node0 * 8 + t;
        hsl[t] = (gi < limit) ? hsrc[gi] : make_uint4(0u, 0u, 0u, 0u);
    }
    for (unsigned i = t; i < sz; i += 512) raw[i] = binned[src0 + i];   // single global pass
    __syncthreads();

    for (unsigned i = t; i < sz; i += 512)
        atomicAdd(&ndeg[raw[i] >> 17], 1u);
    __syncthreads();

    // single-wave inclusive scan over 64 bucket-degrees (threads 0..63 = wave 0)
    if (t < BNODES) {
        const unsigned d = ndeg[t];
        unsigned sc = d;
#pragma unroll
        for (int st = 1; st < BNODES; st <<= 1) {
            const unsigned o = __shfl_up(sc, st, 64);
            if (t >= st) sc += o;
        }
        nbase[t] = sc - d;
        ncur[t]  = sc - d;
    }
    __syncthreads();

    for (unsigned i = t; i < sz; i += 512) {
        const unsigned p = raw[i];
        const unsigned pos = atomicAdd(&ncur[p >> 17], 1u);
        stg[pos] = p & 0x1FFFFu;
    }
    __syncthreads();

    // ---------------- node phase: 16 processors (32 lanes each), 4 nodes per processor ----------------
    const int lane  = t & 63;
    const int half  = lane >> 5;
    const int slot4 = (lane >> 3) & 3;
    const int q     = lane & 7;
    const int proc  = (t >> 6) * 2 + half;    // 0..15
    const char* h16 = (const char*)h16v;

    float b1[8], a2b[8], a3b[8], a0m[8];
#pragma unroll
    for (int f = 0; f < 8; ++f) {
        const float A0 = a[q * 8 + f];
        const float A1 = a[64 + q * 8 + f];
        const float A2 = a[128 + q * 8 + f];
        const float A3 = a[192 + q * 8 + f];
        b1[f]  = fmaf(LK_A, A2 - A3, A1);
        a2b[f] = LK_B * A2;
        a3b[f] = LK_B * A3;
        a0m[f] = fmaf(LK_A, A2 + A3, A0);
    }

#pragma unroll 1
    for (int nn = 0; nn < BNODES / 16; ++nn) {
        const int nloc = proc * (BNODES / 16) + nn;
        const int node = node0 + nloc;
        const int beg = (int)nbase[nloc];
        const int len = (int)ndeg[nloc];

        float hs[8]; cvt8(hsl[nloc * 8 + q], hs);
        float csp = 0.f;
#pragma unroll
        for (int f = 0; f < 8; ++f) csp = fmaf(hs[f], a0m[f], csp);
        const float cs = sum8(csp);

        float acc[8];
#pragma unroll
        for (int f = 0; f < 8; ++f) acc[f] = 0.f;
        float rsum = 0.f;

        const int lm1 = (len > 0) ? len - 1 : 0;
        int dA = 0;
        if (len > 0) { int e0 = slot4; if (e0 > lm1) e0 = lm1; dA = (int)stg[beg + e0]; }
        uint4 uA = *(const uint4*)(h16 + ((size_t)dA << 7) + q * 16);
        int dB = dA;
        if (len > 4) { int e1 = 4 + slot4; if (e1 > lm1) e1 = lm1; dB = (int)stg[beg + e1]; }
        uint4 uB = *(const uint4*)(h16 + ((size_t)dB << 7) + q * 16);
        int dC = dB;
        if (len > 8) { int e2 = 8 + slot4; if (e2 > lm1) e2 = lm1; dC = (int)stg[beg + e2]; }

        for (int cb = 0; cb < len; cb += 4) {
            uint4 uC = uB;
            int dD = dC;
            if (cb + 8 < len)
                uC = *(const uint4*)(h16 + ((size_t)dC << 7) + q * 16);   // 2 chunks ahead
            if (cb + 12 < len) { int e3 = cb + 12 + slot4; if (e3 > lm1) e3 = lm1; dD = (int)stg[beg + e3]; }

            float g[8];
            cvt8(uA, g);
            float p0 = 0.f, p1 = 0.f;
#pragma unroll
            for (int f = 0; f < 8; f += 2) {
                const float sa0 = hs[f] + g[f],         sb0 = hs[f] - g[f];
                const float sa1 = hs[f + 1] + g[f + 1], sb1 = hs[f + 1] - g[f + 1];
                p0 = fmaf(g[f],     b1[f],     p0);
                p1 = fmaf(g[f + 1], b1[f + 1], p1);
                p0 = fmaf(fabsf(sa0), a2b[f],     p0);
                p1 = fmaf(fabsf(sa1), a2b[f + 1], p1);
                p0 = fmaf(fabsf(sb0), a3b[f],     p0);
                p1 = fmaf(fabsf(sb1), a3b[f + 1], p1);
            }
            const float R = sum8(p0 + p1);

            float e = __expf(-leaky(cs + R));
            e = (cb + slot4 < len) ? e : 0.f;
#pragma unroll
            for (int f = 0; f < 8; ++f) acc[f] = fmaf(e, g[f], acc[f]);
            rsum += e;

            uA = uB; uB = uC; dC = dD;
        }

#pragma unroll
        for (int f = 0; f < 8; ++f) acc[f] = xslot_sum2(acc[f]);
        rsum = xslot_sum2(rsum);

        if (slot4 == 0 && node < N) {
            const float inv = 1.f / (rsum + 1e-16f);
            float4 o0, o1;
            o0.x = acc[0] * inv; o0.y = acc[1] * inv; o0.z = acc[2] * inv; o0.w = acc[3] * inv;
            o1.x = acc[4] * inv; o1.y = acc[5] * inv; o1.z = acc[6] * inv; o1.w = acc[7] * inv;
            float* orow = out + (size_t)node * F_OUT + q * 8;
            *(float4*)orow = o0;
            *(float4*)(orow + 4) = o1;
        }
    }
}

// ---------------- Plan B: old CSR build + compact node kernel ----------------
__global__ __launch_bounds__(256) void hist_kernel(const int* __restrict__ ei,
                                                   unsigned* __restrict__ cnt, int E) {
    const int e = blockIdx.x * 256 + threadIdx.x;
    if (e < E) atomicAdd(&cnt[ei[e]], 1u);
}

__global__ __launch_bounds__(256) void scan1(const unsigned* __restrict__ cnt,
                                             unsigned* __restrict__ bsum, int n) {
    __shared__ unsigned lds[256];
    const int t = threadIdx.x;
    const int base = blockIdx.x * 2048 + t * 8;
    unsigned s = 0;
#pragma unroll
    for (int i = 0; i < 8; ++i) { const int idx = base + i; if (idx < n) s += cnt[idx]; }
    lds[t] = s; __syncthreads();
    for (int st = 128; st > 0; st >>= 1) {
        if (t < st) lds[t] += lds[t + st];
        __syncthreads();
    }
    if (t == 0) bsum[blockIdx.x] = lds[0];
}

__global__ __launch_bounds__(128) void scan2(unsigned* __restrict__ bsum,
                                             unsigned* __restrict__ off, int nb, int n) {
    __shared__ unsigned lds[128];
    const int t = threadIdx.x;
    if (t < nb) lds[t] = bsum[t];
    __syncthreads();
    if (t == 0) {
        unsigned run = 0;
        for (int i = 0; i < nb; ++i) { const unsigned v = lds[i]; lds[i] = run; run += v; }
        off[n] = run;
    }
    __syncthreads();
    if (t < nb) bsum[t] = lds[t];
}

__global__ __launch_bounds__(256) void scan3(const unsigned* __restrict__ cnt,
                                             const unsigned* __restrict__ bsum,
                                             unsigned* __restrict__ off,
                                             unsigned* __restrict__ cursor, int n) {
    __shared__ unsigned lds[256];
    const int t = threadIdx.x;
    const int base = blockIdx.x * 2048 + t * 8;
    unsigned v[8]; unsigned s = 0;
#pragma unroll
    for (int i = 0; i < 8; ++i) { const int idx = base + i; v[i] = (idx < n) ? cnt[idx] : 0u; s += v[i]; }
    lds[t] = s; __syncthreads();
    for (int st = 1; st < 256; st <<= 1) {
        const unsigned add = (t >= st) ? lds[t - st] : 0u;
        __syncthreads();
        lds[t] += add;
        __syncthreads();
    }
    unsigned excl = (t > 0 ? lds[t - 1] : 0u) + bsum[blockIdx.x];
#pragma unroll
    for (int i = 0; i < 8; ++i) {
        const int idx = base + i;
        if (idx < n) { off[idx] = excl; cursor[idx] = excl; excl += v[i]; }
    }
}

__global__ __launch_bounds__(256) void scatter_kernel(const int* __restrict__ ei,
                                                      unsigned* __restrict__ cursor,
                                                      int* __restrict__ sdst, int E) {
    const int e = blockIdx.x * 256 + threadIdx.x;
    if (e >= E) return;
    const int s = ei[e];
    const int d = ei[E + e];
    const unsigned pos = atomicAdd(&cursor[s], 1u);
    sdst[pos] = d;
}

__global__ __launch_bounds__(256) void node_kernel(const unsigned* __restrict__ off,
                                                   const unsigned* __restrict__ deg,
                                                   const int* __restrict__ sdst,
                                                   const uint2* __restrict__ h16v,
                                                   const float* __restrict__ a,
                                                   float* __restrict__ out, int N) {
    const int lane  = threadIdx.x & 63;
    const int half  = lane >> 5;
    const int slot4 = (lane >> 3) & 3;
    const int q     = lane & 7;
    const char* h16 = (const char*)h16v;

    float b1[8], a2b[8], a3b[8], a0m[8];
#pragma unroll
    for (int f = 0; f < 8; ++f) {
        const float A0 = a[q * 8 + f];
        const float A1 = a[64 + q * 8 + f];
        const float A2 = a[128 + q * 8 + f];
        const float A3 = a[192 + q * 8 + f];
        b1[f]  = fmaf(LK_A, A2 - A3, A1);
        a2b[f] = LK_B * A2;
        a3b[f] = LK_B * A3;
        a0m[f] = fmaf(LK_A, A2 + A3, A0);
    }

    const int wid = (int)((blockIdx.x * 256u + threadIdx.x) >> 6);
    const int nw  = (int)((gridDim.x * 256u) >> 6);

    for (int pr = wid; pr * 2 < N; pr += nw) {
        const int node = pr * 2 + half;
        const int nc = (node < N) ? node : N - 1;
        const unsigned beg = off[nc];
        const int len = (node < N) ? (int)deg[nc] : 0;

        float hs[8];
        cvt8(*(const uint4*)(h16 + ((size_t)nc << 7) + q * 16), hs);
        float csp = 0.f;
#pragma unroll
        for (int f = 0; f < 8; ++f) csp = fmaf(hs[f], a0m[f], csp);
        const float cs = sum8(csp);

        const int lenO = __shfl_xor(len, 32);
        const int ml = (len > lenO) ? len : lenO;

        float acc[8];
#pragma unroll
        for (int f = 0; f < 8; ++f) acc[f] = 0.f;
        float rsum = 0.f;

        const int lm1 = (len > 0) ? len - 1 : 0;
        int dA = 0;
        if (len > 0) { int e0 = slot4; if (e0 > lm1) e0 = lm1; dA = sdst[beg + e0]; }
        uint4 uA = *(const uint4*)(h16 + ((size_t)dA << 7) + q * 16);
        int dB = dA;
        if (len > 4) { int e1 = 4 + slot4; if (e1 > lm1) e1 = lm1; dB = sdst[beg + e1]; }
        uint4 uB = *(const uint4*)(h16 + ((size_t)dB << 7) + q * 16);
        int dC = dB;
        if (len > 8) { int e2 = 8 + slot4; if (e2 > lm1) e2 = lm1; dC = sdst[beg + e2]; }

        for (int cb = 0; cb < ml; cb += 4) {
            uint4 uC = uB;
            int dD = dC;
            if (cb + 8 < len)
                uC = *(const uint4*)(h16 + ((size_t)dC << 7) + q * 16);
            if (cb + 12 < len) { int e3 = cb + 12 + slot4; if (e3 > lm1) e3 = lm1; dD = sdst[beg + e3]; }

            float g[8];
            cvt8(uA, g);
            float p0 = 0.f, p1 = 0.f;
#pragma unroll
            for (int f = 0; f < 8; f += 2) {
                const float sa0 = hs[f] + g[f],         sb0 = hs[f] - g[f];
                const float sa1 = hs[f + 1] + g[f + 1], sb1 = hs[f + 1] - g[f + 1];
                p0 = fmaf(g[f],     b1[f],     p0);
                p1 = fmaf(g[f + 1], b1[f + 1], p1);
                p0 = fmaf(fabsf(sa0), a2b[f],     p0);
                p1 = fmaf(fabsf(sa1), a2b[f + 1], p1);
                p0 = fmaf(fabsf(sb0), a3b[f],     p0);
                p1 = fmaf(fabsf(sb1), a3b[f + 1], p1);
            }
            const float R = sum8(p0 + p1);
            float e = __expf(-leaky(cs + R));
            e = (cb + slot4 < len) ? e : 0.f;
#pragma unroll
            for (int f = 0; f < 8; ++f) acc[f] = fmaf(e, g[f], acc[f]);
            rsum += e;
            uA = uB; uB = uC; dC = dD;
        }

#pragma unroll
        for (int f = 0; f < 8; ++f) acc[f] = xslot_sum2(acc[f]);
        rsum = xslot_sum2(rsum);

        if (slot4 == 0 && node < N) {
            const float inv = 1.f / (rsum + 1e-16f);
            float4 o0, o1;
            o0.x = acc[0] * inv; o0.y = acc[1] * inv; o0.z = acc[2] * inv; o0.w = acc[3] * inv;
            o1.x = acc[4] * inv; o1.y = acc[5] * inv; o1.z = acc[6] * inv; o1.w = acc[7] * inv;
            float* orow = out + (size_t)node * F_OUT + q * 8;
            *(float4*)orow = o0;
            *(float4*)(orow + 4) = o1;
        }
    }
}

// ---------------- Plan C: atomic fallback ----------------
__device__ __forceinline__ float edge_part(float hs, float hd, float a1, float a2, float a3) {
    float p = hd * a1;
    p = fmaf(leaky(hs + hd), a2, p);
    p = fmaf(leaky(hs - hd), a3, p);
    return p;
}

__global__ __launch_bounds__(256) void edge_kernel(const int* __restrict__ ei,
                                                   const float* __restrict__ h,
                                                   const float* __restrict__ a,
                                                   float* __restrict__ hprime,
                                                   float* __restrict__ rowsum,
                                                   int E) {
    const int lane = threadIdx.x & 63;
    const int wave = (int)((blockIdx.x * blockDim.x + threadIdx.x) >> 6);
    const int nwaves = (int)((gridDim.x * blockDim.x) >> 6);
    const float a0 = a[lane], a1 = a[64 + lane], a2 = a[128 + lane], a3 = a[192 + lane];
    for (int e = wave; e < E; e += nwaves) {
        const int s = ei[e];
        const int d = ei[E + e];
        const float hs = h[(size_t)s * F_OUT + lane];
        const float hd = h[(size_t)d * F_OUT + lane];
        const float part = wave_sum(hs * a0 + edge_part(hs, hd, a1, a2, a3));
        const float ee = __expf(-leaky(part));
        atomicAdd(&hprime[(size_t)s * F_OUT + lane], ee * hd);
        if (lane == 0) atomicAdd(&rowsum[s], ee);
    }
}

__global__ __launch_bounds__(256) void finalize(float* __restrict__ out,
                                                const float* __restrict__ rowsum,
                                                int total) {
    const int i = blockIdx.x * blockDim.x + threadIdx.x;
    if (i < total) out[i] = out[i] / (rowsum[i >> 6] + 1e-16f);
}

static inline size_t align_up(size_t v, size_t a) { return (v + a - 1) & ~(a - 1); }

extern "C" void kernel_launch(void* const* d_in, const int* in_sizes, int n_in,
                              void* d_out, int out_size, void* d_ws, size_t ws_size,
                              hipStream_t stream) {
    const float* x  = (const float*)d_in[0];
    const int*   ei = (const int*)d_in[1];
    const float* W  = (const float*)d_in[2];
    const float* a  = (const float*)d_in[3];

    const int N = in_sizes[0] / F_IN;
    const int E = in_sizes[1] / 2;
    float* out = (float*)d_out;

    const int NB = (N + BNODES - 1) >> BSHIFT;
    const int ngemm = (N + 127) / 128;
    const int nbt = (E + BIN_TILE - 1) / BIN_TILE;
    const unsigned meanFill = (NB > 0) ? (unsigned)(E / NB) : 0u;

    char* ws = (char*)d_ws;
    const size_t szh16  = align_up((size_t)N * F_OUT * 2, 256);
    const size_t szoff  = align_up(((size_t)N + 1) * 4, 256);
    const size_t szedge = align_up((size_t)E * 4 + 64, 256);
    const size_t szbin  = align_up((size_t)NB * BCAP * 4 + 64, 256);

    // plan A: h16 | binned | gcur
    const size_t binned_b = szh16;
    const size_t gcurA_b  = binned_b + szbin;
    const size_t needA    = gcurA_b + align_up((size_t)NB * 4, 256);
    // plan B: h16 | off | deg | sdst | cursor | bsum
    const size_t offB_b   = szh16;
    const size_t degB_b   = offB_b + szoff;
    const size_t sdstB_b  = degB_b + szoff;
    const size_t cursor_b = sdstB_b + szedge;
    const size_t bsum_b   = cursor_b + align_up((size_t)N * 4, 256);
    const size_t needB    = bsum_b + 4096;

    uint2* h16 = (uint2*)ws;

    if (ws_size >= needA && N <= (1 << 17) && NB <= 4096 && meanFill <= (BCAP * 3u) / 4u) {
        unsigned* binned = (unsigned*)(ws + binned_b);
        unsigned* gcur   = (unsigned*)(ws + gcurA_b);

        hipMemsetAsync(gcur, 0, (size_t)NB * 4, stream);
        gemm_binA<<<ngemm + nbt, 256, 0, stream>>>(x, W, nullptr, h16, ei, gcur, binned,
                                                   N, E, NB, ngemm, BCAP, 1);
        bucket_node<<<NB, 512, 0, stream>>>(binned, gcur, h16, a, out, N, BCAP);
    } else if (ws_size >= needB && N <= (1 << 17)) {
        unsigned* off    = (unsigned*)(ws + offB_b);
        unsigned* deg    = (unsigned*)(ws + degB_b);
        int*      sdst   = (int*)(ws + sdstB_b);
        unsigned* cursor = (unsigned*)(ws + cursor_b);
        unsigned* bsum   = (unsigned*)(ws + bsum_b);
        const int nb2 = (N + 2047) / 2048;

        hipMemsetAsync(deg, 0, (size_t)N * 4, stream);
        gemm_binA<<<ngemm, 256, 0, stream>>>(x, W, nullptr, h16, ei, nullptr, nullptr,
                                             N, E, NB, ngemm, BCAP, 1);
        hist_kernel<<<(E + 255) / 256, 256, 0, stream>>>(ei, deg, E);
        scan1<<<nb2, 256, 0, stream>>>(deg, bsum, N);
        scan2<<<1, 128, 0, stream>>>(bsum, off, nb2, N);
        scan3<<<nb2, 256, 0, stream>>>(deg, bsum, off, cursor, N);
        scatter_kernel<<<(E + 255) / 256, 256, 0, stream>>>(ei, cursor, sdst, E);
        node_kernel<<<2048, 256, 0, stream>>>(off, deg, sdst, h16, a, out, N);
    } else {
        float* h32    = (float*)ws;
        float* rowsum = (float*)(ws + align_up((size_t)N * F_OUT * 4, 256));
        hipMemsetAsync(d_out, 0, (size_t)N * F_OUT * sizeof(float), stream);
        hipMemsetAsync(rowsum, 0, (size_t)N * sizeof(float), stream);
        gemm_binA<<<ngemm, 256, 0, stream>>>(x, W, h32, nullptr, ei, nullptr, nullptr,
                                             N, E, NB, ngemm, BCAP, 2);
        edge_kernel<<<2048, 256, 0, stream>>>(ei, h32, a, out, rowsum, E);
        finalize<<<((size_t)N * F_OUT + 255) / 256, 256, 0, stream>>>(out, rowsum, N * F_OUT);
    }
}

// Round 18
// 126.003 us; speedup vs baseline: 1.4919x; 1.0421x over previous
//
#include <hip/hip_runtime.h>
#include <hip/hip_fp16.h>

#define F_IN 128
#define F_OUT 64
#define BIN_TILE 2048
#define BSHIFT 6            // 64 nodes per bucket
#define BNODES 64
#define BCAP 2048u          // per-bucket capacity (mean fill ~1024 at E=1.6M,NB=1563)

#define LK_A 0.505f         // leaky(v) = LK_A*v + LK_B*|v| == leaky_relu(v, 0.01)
#define LK_B 0.495f

__device__ __forceinline__ float leaky(float v) {
    return fmaf(LK_B, fabsf(v), LK_A * v);
}

template <int CTRL>
__device__ __forceinline__ float dppadd(float v) {
    return v + __builtin_bit_cast(float,
        __builtin_amdgcn_update_dpp(0, __builtin_bit_cast(int, v), CTRL, 0xf, 0xf, true));
}

// sum across each 8-lane group (pure VALU DPP); every lane gets its group's sum
__device__ __forceinline__ float sum8(float v) {
    v = dppadd<0xB1>(v);    // quad_perm [1,0,3,2]  (xor 1)
    v = dppadd<0x4E>(v);    // quad_perm [2,3,0,1]  (xor 2)
    v = dppadd<0x141>(v);   // row_half_mirror      (xor 7 within 8)
    return v;
}

// combine the 4 edge-slots of a 32-lane HALF, preserving q (lane&7)
__device__ __forceinline__ float xslot_sum2(float v) {
    v = dppadd<0x128>(v);   // row_ror:8 -> lane ^ 8 (q preserved)
    v += __shfl_xor(v, 16);
    return v;
}

// Full-wave (64-lane) sum via DPP (plan-C fallback helper)
__device__ __forceinline__ float wave_sum(float v) {
    v += __builtin_bit_cast(float, __builtin_amdgcn_update_dpp(0, __builtin_bit_cast(int, v), 0x111, 0xf, 0xf, true));
    v += __builtin_bit_cast(float, __builtin_amdgcn_update_dpp(0, __builtin_bit_cast(int, v), 0x112, 0xf, 0xf, true));
    v += __builtin_bit_cast(float, __builtin_amdgcn_update_dpp(0, __builtin_bit_cast(int, v), 0x114, 0xf, 0xe, true));
    v += __builtin_bit_cast(float, __builtin_amdgcn_update_dpp(0, __builtin_bit_cast(int, v), 0x118, 0xf, 0xc, true));
    v += __builtin_bit_cast(float, __builtin_amdgcn_update_dpp(0, __builtin_bit_cast(int, v), 0x142, 0xa, 0xf, true));
    v += __builtin_bit_cast(float, __builtin_amdgcn_update_dpp(0, __builtin_bit_cast(int, v), 0x143, 0xc, 0xf, true));
    return __builtin_bit_cast(float, __builtin_amdgcn_readlane(__builtin_bit_cast(int, v), 63));
}

__device__ __forceinline__ void cvt8(const uint4 u, float* g) {
    float2 f;
    f = __half22float2(__builtin_bit_cast(__half2, u.x)); g[0] = f.x; g[1] = f.y;
    f = __half22float2(__builtin_bit_cast(__half2, u.y)); g[2] = f.x; g[3] = f.y;
    f = __half22float2(__builtin_bit_cast(__half2, u.z)); g[4] = f.x; g[5] = f.y;
    f = __half22float2(__builtin_bit_cast(__half2, u.w)); g[6] = f.x; g[7] = f.y;
}

// ---------------- Kernel 1: fused [gemm blocks | binA blocks], 32 KB LDS ----------------
// gemm: 64 rows x 64 cols per block, 4 rows/thread, 2-deep x prefetch.
// gcur semantics: offset WITHIN bucket (memset-0 seeded).
__global__ __launch_bounds__(256) void gemm_binA(const float* __restrict__ x,
                                                 const float* __restrict__ W,
                                                 float* __restrict__ h32,
                                                 uint2* __restrict__ h16,
                                                 const int* __restrict__ ei,
                                                 unsigned* __restrict__ gcur,
                                                 unsigned* __restrict__ binned,
                                                 int N, int E, int NB, int ngemm,
                                                 unsigned cap, int mode) {
    __shared__ unsigned smem_u[8192];   // 32 KB shared by both paths

    if ((int)blockIdx.x < ngemm) {
        // ---------- gemm path ----------
        float (*w_lds)[F_OUT] = (float (*)[F_OUT])smem_u;
        {
            const float4* Wv = (const float4*)W;
            float4* wl = (float4*)w_lds;
            for (int i = threadIdx.x; i < F_IN * F_OUT / 4; i += 256) wl[i] = Wv[i];
        }
        __syncthreads();

        const int cg = threadIdx.x & 15;   // 4 cols
        const int rs = threadIdx.x >> 4;   // 16 row slots
        const int row0 = blockIdx.x * 64 + rs * 4;

        int r[4];
#pragma unroll
        for (int i = 0; i < 4; ++i) { const int rr = row0 + i; r[i] = rr < N ? rr : N - 1; }

        float4 acc[4];
#pragma unroll
        for (int i = 0; i < 4; ++i) acc[i] = make_float4(0.f, 0.f, 0.f, 0.f);

        float4 xa[4], xb[4];
#pragma unroll
        for (int i = 0; i < 4; ++i) xa[i] = *(const float4*)(x + (size_t)r[i] * F_IN);
#pragma unroll
        for (int i = 0; i < 4; ++i) xb[i] = *(const float4*)(x + (size_t)r[i] * F_IN + 4);

        for (int k4 = 0; k4 < 32; ++k4) {
            float4 xn[4];
            if (k4 < 30) {
#pragma unroll
                for (int i = 0; i < 4; ++i)
                    xn[i] = *(const float4*)(x + (size_t)r[i] * F_IN + (k4 + 2) * 4);
            }
            float4 wv[4];
#pragma unroll
            for (int kk = 0; kk < 4; ++kk)
                wv[kk] = *(const float4*)&w_lds[k4 * 4 + kk][cg * 4];

#pragma unroll
            for (int i = 0; i < 4; ++i) {
                acc[i].x = fmaf(xa[i].x, wv[0].x, acc[i].x);
                acc[i].y = fmaf(xa[i].x, wv[0].y, acc[i].y);
                acc[i].z = fmaf(xa[i].x, wv[0].z, acc[i].z);
                acc[i].w = fmaf(xa[i].x, wv[0].w, acc[i].w);
                acc[i].x = fmaf(xa[i].y, wv[1].x, acc[i].x);
                acc[i].y = fmaf(xa[i].y, wv[1].y, acc[i].y);
                acc[i].z = fmaf(xa[i].y, wv[1].z, acc[i].z);
                acc[i].w = fmaf(xa[i].y, wv[1].w, acc[i].w);
                acc[i].x = fmaf(xa[i].z, wv[2].x, acc[i].x);
                acc[i].y = fmaf(xa[i].z, wv[2].y, acc[i].y);
                acc[i].z = fmaf(xa[i].z, wv[2].z, acc[i].z);
                acc[i].w = fmaf(xa[i].z, wv[2].w, acc[i].w);
                acc[i].x = fmaf(xa[i].w, wv[3].x, acc[i].x);
                acc[i].y = fmaf(xa[i].w, wv[3].y, acc[i].y);
                acc[i].z = fmaf(xa[i].w, wv[3].z, acc[i].z);
                acc[i].w = fmaf(xa[i].w, wv[3].w, acc[i].w);
            }
#pragma unroll
            for (int i = 0; i < 4; ++i) { xa[i] = xb[i]; }
            if (k4 < 30) {
#pragma unroll
                for (int i = 0; i < 4; ++i) xb[i] = xn[i];
            }
        }

#pragma unroll
        for (int i = 0; i < 4; ++i) {
            const int rr = row0 + i;
            if (rr < N) {
                if (mode & 2) *(float4*)(h32 + (size_t)rr * F_OUT + cg * 4) = acc[i];
                if (mode & 1) {
                    uint2 u;
                    u.x = __builtin_bit_cast(unsigned, __floats2half2_rn(acc[i].x, acc[i].y));
                    u.y = __builtin_bit_cast(unsigned, __floats2half2_rn(acc[i].z, acc[i].w));
                    h16[(size_t)rr * 16 + cg] = u;
                }
            }
        }
    } else {
        // ---------- binA path: 2048 edges/block, bucket-local binning ----------
        unsigned* lcnt  = smem_u;        // [NB]
        unsigned* lbase = smem_u + NB;   // [NB]
        const int t = threadIdx.x;
        for (int i = t; i < NB; i += 256) lcnt[i] = 0;
        __syncthreads();
        const int base = ((int)blockIdx.x - ngemm) * BIN_TILE;
        unsigned pk[8], bk[8], rk[8];
#pragma unroll
        for (int i = 0; i < 8; ++i) {
            const int e = base + i * 256 + t;
            if (e < E) {
                const unsigned s = (unsigned)ei[e];
                const unsigned d = (unsigned)ei[E + e];
                bk[i] = s >> BSHIFT;
                pk[i] = ((s & (BNODES - 1u)) << 17) | d;
                rk[i] = atomicAdd(&lcnt[bk[i]], 1u);
            }
        }
        __syncthreads();
        for (int i = t; i < NB; i += 256) {
            const unsigned c = lcnt[i];
            lbase[i] = c ? atomicAdd(&gcur[i], c) : 0u;   // bucket-local base
        }
        __syncthreads();
#pragma unroll
        for (int i = 0; i < 8; ++i) {
            const int e = base + i * 256 + t;
            if (e < E) {
                const unsigned po = lbase[bk[i]] + rk[i];
                if (po < cap) binned[(size_t)bk[i] * cap + po] = pk[i];
            }
        }
    }
}

// ---------------- Kernel 2: fused binB + node compute, 512 thr, one block per 64-node bucket ----------------
// Single global pass over binned; cross-node gather pipeline in the node phase.
__global__ __launch_bounds__(512) void bucket_node(const unsigned* __restrict__ binned,
                                                   const unsigned* __restrict__ gcur,
                                                   const uint2* __restrict__ h16v,
                                                   const float* __restrict__ a,
                                                   float* __restrict__ out,
                                                   int N, unsigned cap) {
    __shared__ unsigned raw[BCAP];          // 8 KB: raw (ungrouped) payloads
    __shared__ unsigned stg[BCAP];          // 8 KB: per-node-grouped dst indices
    __shared__ uint4    hsl[BNODES * 8];    // 8 KB: hs rows for this bucket
    __shared__ unsigned ndeg[BNODES];
    __shared__ unsigned nbase[BNODES];
    __shared__ unsigned ncur[BNODES];

    const int b = blockIdx.x;
    const int t = threadIdx.x;
    const int node0 = b << BSHIFT;
    const size_t src0 = (size_t)b * cap;
    unsigned sz = gcur[b]; if (sz > cap) sz = cap;

    if (t < BNODES) ndeg[t] = 0;
    {   // stage this bucket's hs rows (coalesced, 8 KB: one uint4 per thread)
        const uint4* hsrc = (const uint4*)h16v;
        const int limit = N * 8;
        const int gi = node0 * 8 + t;
        hsl[t] = (gi < limit) ? hsrc[gi] : make_uint4(0u, 0u, 0u, 0u);
    }
    for (unsigned i = t; i < sz; i += 512) raw[i] = binned[src0 + i];   // single global pass
    __syncthreads();

    for (unsigned i = t; i < sz; i += 512)
        atomicAdd(&ndeg[raw[i] >> 17], 1u);
    __syncthreads();

    // single-wave inclusive scan over 64 bucket-degrees (threads 0..63 = wave 0)
    if (t < BNODES) {
        const unsigned d = ndeg[t];
        unsigned sc = d;
#pragma unroll
        for (int st = 1; st < BNODES; st <<= 1) {
            const unsigned o = __shfl_up(sc, st, 64);
            if (t >= st) sc += o;
        }
        nbase[t] = sc - d;
        ncur[t]  = sc - d;
    }
    __syncthreads();

    for (unsigned i = t; i < sz; i += 512) {
        const unsigned p = raw[i];
        const unsigned pos = atomicAdd(&ncur[p >> 17], 1u);
        stg[pos] = p & 0x1FFFFu;
    }
    __syncthreads();

    // ---------------- node phase: 16 processors (32 lanes each), 4 nodes each, cross-node pipeline ----------------
    const int lane  = t & 63;
    const int half  = lane >> 5;
    const int slot4 = (lane >> 3) & 3;
    const int q     = lane & 7;
    const int proc  = (t >> 6) * 2 + half;    // 0..15
    const char* h16 = (const char*)h16v;
    const int PN = BNODES / 16;               // 4 nodes per processor

    float b1[8], a2b[8], a3b[8], a0m[8];
#pragma unroll
    for (int f = 0; f < 8; ++f) {
        const float A0 = a[q * 8 + f];
        const float A1 = a[64 + q * 8 + f];
        const float A2 = a[128 + q * 8 + f];
        const float A3 = a[192 + q * 8 + f];
        b1[f]  = fmaf(LK_A, A2 - A3, A1);
        a2b[f] = LK_B * A2;
        a3b[f] = LK_B * A3;
        a0m[f] = fmaf(LK_A, A2 + A3, A0);
    }

    // prime node 0's first gather
    int begN = (int)nbase[proc * PN];
    int lenN = (int)ndeg[proc * PN];
    int dN = 0;
    if (lenN > 0) { int e0 = slot4; const int lm = lenN - 1; if (e0 > lm) e0 = lm; dN = (int)stg[begN + e0]; }
    uint4 uN = *(const uint4*)(h16 + ((size_t)dN << 7) + q * 16);

#pragma unroll 1
    for (int nn = 0; nn < PN; ++nn) {
        const int nloc = proc * PN + nn;
        const int node = node0 + nloc;
        const int beg = begN;
        const int len = lenN;
        uint4 uA = uN;     // prefetched during previous node's compute

        // issue NEXT node's first gather before this node's compute
        if (nn + 1 < PN) {
            begN = (int)nbase[nloc + 1];
            lenN = (int)ndeg[nloc + 1];
            int d0 = 0;
            if (lenN > 0) { int e0 = slot4; const int lm = lenN - 1; if (e0 > lm) e0 = lm; d0 = (int)stg[begN + e0]; }
            dN = d0;
            uN = *(const uint4*)(h16 + ((size_t)dN << 7) + q * 16);
        }

        float hs[8]; cvt8(hsl[nloc * 8 + q], hs);
        float csp = 0.f;
#pragma unroll
        for (int f = 0; f < 8; ++f) csp = fmaf(hs[f], a0m[f], csp);
        const float cs = sum8(csp);

        float acc[8];
#pragma unroll
        for (int f = 0; f < 8; ++f) acc[f] = 0.f;
        float rsum = 0.f;

        const int lm1 = (len > 0) ? len - 1 : 0;
        int dB = 0;
        if (len > 4) { int e1 = 4 + slot4; if (e1 > lm1) e1 = lm1; dB = (int)stg[beg + e1]; }
        else dB = dN;  // harmless placeholder
        uint4 uB = *(const uint4*)(h16 + ((size_t)dB << 7) + q * 16);
        int dC = dB;
        if (len > 8) { int e2 = 8 + slot4; if (e2 > lm1) e2 = lm1; dC = (int)stg[beg + e2]; }

        for (int cb = 0; cb < len; cb += 4) {
            uint4 uC = uB;
            int dD = dC;
            if (cb + 8 < len)
                uC = *(const uint4*)(h16 + ((size_t)dC << 7) + q * 16);   // 2 chunks ahead
            if (cb + 12 < len) { int e3 = cb + 12 + slot4; if (e3 > lm1) e3 = lm1; dD = (int)stg[beg + e3]; }

            float g[8];
            cvt8(uA, g);
            float p0 = 0.f, p1 = 0.f;
#pragma unroll
            for (int f = 0; f < 8; f += 2) {
                const float sa0 = hs[f] + g[f],         sb0 = hs[f] - g[f];
                const float sa1 = hs[f + 1] + g[f + 1], sb1 = hs[f + 1] - g[f + 1];
                p0 = fmaf(g[f],     b1[f],     p0);
                p1 = fmaf(g[f + 1], b1[f + 1], p1);
                p0 = fmaf(fabsf(sa0), a2b[f],     p0);
                p1 = fmaf(fabsf(sa1), a2b[f + 1], p1);
                p0 = fmaf(fabsf(sb0), a3b[f],     p0);
                p1 = fmaf(fabsf(sb1), a3b[f + 1], p1);
            }
            const float R = sum8(p0 + p1);

            float e = __expf(-leaky(cs + R));
            e = (cb + slot4 < len) ? e : 0.f;
#pragma unroll
            for (int f = 0; f < 8; ++f) acc[f] = fmaf(e, g[f], acc[f]);
            rsum += e;

            uA = uB; uB = uC; dC = dD;
        }

#pragma unroll
        for (int f = 0; f < 8; ++f) acc[f] = xslot_sum2(acc[f]);
        rsum = xslot_sum2(rsum);

        if (slot4 == 0 && node < N) {
            const float inv = 1.f / (rsum + 1e-16f);
            float4 o0, o1;
            o0.x = acc[0] * inv; o0.y = acc[1] * inv; o0.z = acc[2] * inv; o0.w = acc[3] * inv;
            o1.x = acc[4] * inv; o1.y = acc[5] * inv; o1.z = acc[6] * inv; o1.w = acc[7] * inv;
            float* orow = out + (size_t)node * F_OUT + q * 8;
            *(float4*)orow = o0;
            *(float4*)(orow + 4) = o1;
        }
    }
}

// ---------------- Plan B: old CSR build + compact node kernel ----------------
__global__ __launch_bounds__(256) void hist_kernel(const int* __restrict__ ei,
                                                   unsigned* __restrict__ cnt, int E) {
    const int e = blockIdx.x * 256 + threadIdx.x;
    if (e < E) atomicAdd(&cnt[ei[e]], 1u);
}

__global__ __launch_bounds__(256) void scan1(const unsigned* __restrict__ cnt,
                                             unsigned* __restrict__ bsum, int n) {
    __shared__ unsigned lds[256];
    const int t = threadIdx.x;
    const int base = blockIdx.x * 2048 + t * 8;
    unsigned s = 0;
#pragma unroll
    for (int i = 0; i < 8; ++i) { const int idx = base + i; if (idx < n) s += cnt[idx]; }
    lds[t] = s; __syncthreads();
    for (int st = 128; st > 0; st >>= 1) {
        if (t < st) lds[t] += lds[t + st];
        __syncthreads();
    }
    if (t == 0) bsum[blockIdx.x] = lds[0];
}

__global__ __launch_bounds__(128) void scan2(unsigned* __restrict__ bsum,
                                             unsigned* __restrict__ off, int nb, int n) {
    __shared__ unsigned lds[128];
    const int t = threadIdx.x;
    if (t < nb) lds[t] = bsum[t];
    __syncthreads();
    if (t == 0) {
        unsigned run = 0;
        for (int i = 0; i < nb; ++i) { const unsigned v = lds[i]; lds[i] = run; run += v; }
        off[n] = run;
    }
    __syncthreads();
    if (t < nb) bsum[t] = lds[t];
}

__global__ __launch_bounds__(256) void scan3(const unsigned* __restrict__ cnt,
                                             const unsigned* __restrict__ bsum,
                                             unsigned* __restrict__ off,
                                             unsigned* __restrict__ cursor, int n) {
    __shared__ unsigned lds[256];
    const int t = threadIdx.x;
    const int base = blockIdx.x * 2048 + t * 8;
    unsigned v[8]; unsigned s = 0;
#pragma unroll
    for (int i = 0; i < 8; ++i) { const int idx = base + i; v[i] = (idx < n) ? cnt[idx] : 0u; s += v[i]; }
    lds[t] = s; __syncthreads();
    for (int st = 1; st < 256; st <<= 1) {
        const unsigned add = (t >= st) ? lds[t - st] : 0u;
        __syncthreads();
        lds[t] += add;
        __syncthreads();
    }
    unsigned excl = (t > 0 ? lds[t - 1] : 0u) + bsum[blockIdx.x];
#pragma unroll
    for (int i = 0; i < 8; ++i) {
        const int idx = base + i;
        if (idx < n) { off[idx] = excl; cursor[idx] = excl; excl += v[i]; }
    }
}

__global__ __launch_bounds__(256) void scatter_kernel(const int* __restrict__ ei,
                                                      unsigned* __restrict__ cursor,
                                                      int* __restrict__ sdst, int E) {
    const int e = blockIdx.x * 256 + threadIdx.x;
    if (e >= E) return;
    const int s = ei[e];
    const int d = ei[E + e];
    const unsigned pos = atomicAdd(&cursor[s], 1u);
    sdst[pos] = d;
}

__global__ __launch_bounds__(256) void node_kernel(const unsigned* __restrict__ off,
                                                   const unsigned* __restrict__ deg,
                                                   const int* __restrict__ sdst,
                                                   const uint2* __restrict__ h16v,
                                                   const float* __restrict__ a,
                                                   float* __restrict__ out, int N) {
    const int lane  = threadIdx.x & 63;
    const int half  = lane >> 5;
    const int slot4 = (lane >> 3) & 3;
    const int q     = lane & 7;
    const char* h16 = (const char*)h16v;

    float b1[8], a2b[8], a3b[8], a0m[8];
#pragma unroll
    for (int f = 0; f < 8; ++f) {
        const float A0 = a[q * 8 + f];
        const float A1 = a[64 + q * 8 + f];
        const float A2 = a[128 + q * 8 + f];
        const float A3 = a[192 + q * 8 + f];
        b1[f]  = fmaf(LK_A, A2 - A3, A1);
        a2b[f] = LK_B * A2;
        a3b[f] = LK_B * A3;
        a0m[f] = fmaf(LK_A, A2 + A3, A0);
    }

    const int wid = (int)((blockIdx.x * 256u + threadIdx.x) >> 6);
    const int nw  = (int)((gridDim.x * 256u) >> 6);

    for (int pr = wid; pr * 2 < N; pr += nw) {
        const int node = pr * 2 + half;
        const int nc = (node < N) ? node : N - 1;
        const unsigned beg = off[nc];
        const int len = (node < N) ? (int)deg[nc] : 0;

        float hs[8];
        cvt8(*(const uint4*)(h16 + ((size_t)nc << 7) + q * 16), hs);
        float csp = 0.f;
#pragma unroll
        for (int f = 0; f < 8; ++f) csp = fmaf(hs[f], a0m[f], csp);
        const float cs = sum8(csp);

        const int lenO = __shfl_xor(len, 32);
        const int ml = (len > lenO) ? len : lenO;

        float acc[8];
#pragma unroll
        for (int f = 0; f < 8; ++f) acc[f] = 0.f;
        float rsum = 0.f;

        const int lm1 = (len > 0) ? len - 1 : 0;
        int dA = 0;
        if (len > 0) { int e0 = slot4; if (e0 > lm1) e0 = lm1; dA = sdst[beg + e0]; }
        uint4 uA = *(const uint4*)(h16 + ((size_t)dA << 7) + q * 16);
        int dB = dA;
        if (len > 4) { int e1 = 4 + slot4; if (e1 > lm1) e1 = lm1; dB = sdst[beg + e1]; }
        uint4 uB = *(const uint4*)(h16 + ((size_t)dB << 7) + q * 16);
        int dC = dB;
        if (len > 8) { int e2 = 8 + slot4; if (e2 > lm1) e2 = lm1; dC = sdst[beg + e2]; }

        for (int cb = 0; cb < ml; cb += 4) {
            uint4 uC = uB;
            int dD = dC;
            if (cb + 8 < len)
                uC = *(const uint4*)(h16 + ((size_t)dC << 7) + q * 16);
            if (cb + 12 < len) { int e3 = cb + 12 + slot4; if (e3 > lm1) e3 = lm1; dD = sdst[beg + e3]; }

            float g[8];
            cvt8(uA, g);
            float p0 = 0.f, p1 = 0.f;
#pragma unroll
            for (int f = 0; f < 8; f += 2) {
                const float sa0 = hs[f] + g[f],         sb0 = hs[f] - g[f];
                const float sa1 = hs[f + 1] + g[f + 1], sb1 = hs[f + 1] - g[f + 1];
                p0 = fmaf(g[f],     b1[f],     p0);
                p1 = fmaf(g[f + 1], b1[f + 1], p1);
                p0 = fmaf(fabsf(sa0), a2b[f],     p0);
                p1 = fmaf(fabsf(sa1), a2b[f + 1], p1);
                p0 = fmaf(fabsf(sb0), a3b[f],     p0);
                p1 = fmaf(fabsf(sb1), a3b[f + 1], p1);
            }
            const float R = sum8(p0 + p1);
            float e = __expf(-leaky(cs + R));
            e = (cb + slot4 < len) ? e : 0.f;
#pragma unroll
            for (int f = 0; f < 8; ++f) acc[f] = fmaf(e, g[f], acc[f]);
            rsum += e;
            uA = uB; uB = uC; dC = dD;
        }

#pragma unroll
        for (int f = 0; f < 8; ++f) acc[f] = xslot_sum2(acc[f]);
        rsum = xslot_sum2(rsum);

        if (slot4 == 0 && node < N) {
            const float inv = 1.f / (rsum + 1e-16f);
            float4 o0, o1;
            o0.x = acc[0] * inv; o0.y = acc[1] * inv; o0.z = acc[2] * inv; o0.w = acc[3] * inv;
            o1.x = acc[4] * inv; o1.y = acc[5] * inv; o1.z = acc[6] * inv; o1.w = acc[7] * inv;
            float* orow = out + (size_t)node * F_OUT + q * 8;
            *(float4*)orow = o0;
            *(float4*)(orow + 4) = o1;
        }
    }
}

// ---------------- Plan C: atomic fallback ----------------
__device__ __forceinline__ float edge_part(float hs, float hd, float a1, float a2, float a3) {
    float p = hd * a1;
    p = fmaf(leaky(hs + hd), a2, p);
    p = fmaf(leaky(hs - hd), a3, p);
    return p;
}

__global__ __launch_bounds__(256) void edge_kernel(const int* __restrict__ ei,
                                                   const float* __restrict__ h,
                                                   const float* __restrict__ a,
                                                   float* __restrict__ hprime,
                                                   float* __restrict__ rowsum,
                                                   int E) {
    const int lane = threadIdx.x & 63;
    const int wave = (int)((blockIdx.x * blockDim.x + threadIdx.x) >> 6);
    const int nwaves = (int)((gridDim.x * blockDim.x) >> 6);
    const float a0 = a[lane], a1 = a[64 + lane], a2 = a[128 + lane], a3 = a[192 + lane];
    for (int e = wave; e < E; e += nwaves) {
        const int s = ei[e];
        const int d = ei[E + e];
        const float hs = h[(size_t)s * F_OUT + lane];
        const float hd = h[(size_t)d * F_OUT + lane];
        const float part = wave_sum(hs * a0 + edge_part(hs, hd, a1, a2, a3));
        const float ee = __expf(-leaky(part));
        atomicAdd(&hprime[(size_t)s * F_OUT + lane], ee * hd);
        if (lane == 0) atomicAdd(&rowsum[s], ee);
    }
}

__global__ __launch_bounds__(256) void finalize(float* __restrict__ out,
                                                const float* __restrict__ rowsum,
                                                int total) {
    const int i = blockIdx.x * blockDim.x + threadIdx.x;
    if (i < total) out[i] = out[i] / (rowsum[i >> 6] + 1e-16f);
}

static inline size_t align_up(size_t v, size_t a) { return (v + a - 1) & ~(a - 1); }

extern "C" void kernel_launch(void* const* d_in, const int* in_sizes, int n_in,
                              void* d_out, int out_size, void* d_ws, size_t ws_size,
                              hipStream_t stream) {
    const float* x  = (const float*)d_in[0];
    const int*   ei = (const int*)d_in[1];
    const float* W  = (const float*)d_in[2];
    const float* a  = (const float*)d_in[3];

    const int N = in_sizes[0] / F_IN;
    const int E = in_sizes[1] / 2;
    float* out = (float*)d_out;

    const int NB = (N + BNODES - 1) >> BSHIFT;
    const int ngemm = (N + 63) / 64;
    const int nbt = (E + BIN_TILE - 1) / BIN_TILE;
    const unsigned meanFill = (NB > 0) ? (unsigned)(E / NB) : 0u;

    char* ws = (char*)d_ws;
    const size_t szh16  = align_up((size_t)N * F_OUT * 2, 256);
    const size_t szoff  = align_up(((size_t)N + 1) * 4, 256);
    const size_t szedge = align_up((size_t)E * 4 + 64, 256);
    const size_t szbin  = align_up((size_t)NB * BCAP * 4 + 64, 256);

    // plan A: h16 | binned | gcur
    const size_t binned_b = szh16;
    const size_t gcurA_b  = binned_b + szbin;
    const size_t needA    = gcurA_b + align_up((size_t)NB * 4, 256);
    // plan B: h16 | off | deg | sdst | cursor | bsum
    const size_t offB_b   = szh16;
    const size_t degB_b   = offB_b + szoff;
    const size_t sdstB_b  = degB_b + szoff;
    const size_t cursor_b = sdstB_b + szedge;
    const size_t bsum_b   = cursor_b + align_up((size_t)N * 4, 256);
    const size_t needB    = bsum_b + 4096;

    uint2* h16 = (uint2*)ws;

    if (ws_size >= needA && N <= (1 << 17) && NB <= 4096 && meanFill <= (BCAP * 3u) / 4u) {
        unsigned* binned = (unsigned*)(ws + binned_b);
        unsigned* gcur   = (unsigned*)(ws + gcurA_b);

        hipMemsetAsync(gcur, 0, (size_t)NB * 4, stream);
        gemm_binA<<<ngemm + nbt, 256, 0, stream>>>(x, W, nullptr, h16, ei, gcur, binned,
                                                   N, E, NB, ngemm, BCAP, 1);
        bucket_node<<<NB, 512, 0, stream>>>(binned, gcur, h16, a, out, N, BCAP);
    } else if (ws_size >= needB && N <= (1 << 17)) {
        unsigned* off    = (unsigned*)(ws + offB_b);
        unsigned* deg    = (unsigned*)(ws + degB_b);
        int*      sdst   = (int*)(ws + sdstB_b);
        unsigned* cursor = (unsigned*)(ws + cursor_b);
        unsigned* bsum   = (unsigned*)(ws + bsum_b);
        const int nb2 = (N + 2047) / 2048;

        hipMemsetAsync(deg, 0, (size_t)N * 4, stream);
        gemm_binA<<<ngemm, 256, 0, stream>>>(x, W, nullptr, h16, ei, nullptr, nullptr,
                                             N, E, NB, ngemm, BCAP, 1);
        hist_kernel<<<(E + 255) / 256, 256, 0, stream>>>(ei, deg, E);
        scan1<<<nb2, 256, 0, stream>>>(deg, bsum, N);
        scan2<<<1, 128, 0, stream>>>(bsum, off, nb2, N);
        scan3<<<nb2, 256, 0, stream>>>(deg, bsum, off, cursor, N);
        scatter_kernel<<<(E + 255) / 256, 256, 0, stream>>>(ei, cursor, sdst, E);
        node_kernel<<<2048, 256, 0, stream>>>(off, deg, sdst, h16, a, out, N);
    } else {
        float* h32    = (float*)ws;
        float* rowsum = (float*)(ws + align_up((size_t)N * F_OUT * 4, 256));
        hipMemsetAsync(d_out, 0, (size_t)N * F_OUT * sizeof(float), stream);
        hipMemsetAsync(rowsum, 0, (size_t)N * sizeof(float), stream);
        gemm_binA<<<ngemm, 256, 0, stream>>>(x, W, h32, nullptr, ei, nullptr, nullptr,
                                             N, E, NB, ngemm, BCAP, 2);
        edge_kernel<<<2048, 256, 0, stream>>>(ei, h32, a, out, rowsum, E);
        finalize<<<((size_t)N * F_OUT + 255) / 256, 256, 0, stream>>>(out, rowsum, N * F_OUT);
    }
}

// Round 19
// 124.846 us; speedup vs baseline: 1.5057x; 1.0093x over previous
//
#include <hip/hip_runtime.h>
#include <hip/hip_fp16.h>

#define F_IN 128
#define F_OUT 64
#define BIN_TILE 2048
#define BSHIFT 6            // 64 nodes per bucket
#define BNODES 64
#define BCAP 2048u          // per-bucket capacity (mean fill ~1024 at E=1.6M,NB=1563)

#define LK_A 0.505f         // leaky(v) = LK_A*v + LK_B*|v| == leaky_relu(v, 0.01)
#define LK_B 0.495f

__device__ __forceinline__ float leaky(float v) {
    return fmaf(LK_B, fabsf(v), LK_A * v);
}

template <int CTRL>
__device__ __forceinline__ float dppadd(float v) {
    return v + __builtin_bit_cast(float,
        __builtin_amdgcn_update_dpp(0, __builtin_bit_cast(int, v), CTRL, 0xf, 0xf, true));
}

// sum across each 8-lane group (pure VALU DPP); every lane gets its group's sum
__device__ __forceinline__ float sum8(float v) {
    v = dppadd<0xB1>(v);    // quad_perm [1,0,3,2]  (xor 1)
    v = dppadd<0x4E>(v);    // quad_perm [2,3,0,1]  (xor 2)
    v = dppadd<0x141>(v);   // row_half_mirror      (xor 7 within 8)
    return v;
}

// combine the 4 edge-slots of a 32-lane HALF, preserving q (lane&7)
__device__ __forceinline__ float xslot_sum2(float v) {
    v = dppadd<0x128>(v);   // row_ror:8 -> lane ^ 8 (q preserved)
    v += __shfl_xor(v, 16);
    return v;
}

// Full-wave (64-lane) sum via DPP (plan-C fallback helper)
__device__ __forceinline__ float wave_sum(float v) {
    v += __builtin_bit_cast(float, __builtin_amdgcn_update_dpp(0, __builtin_bit_cast(int, v), 0x111, 0xf, 0xf, true));
    v += __builtin_bit_cast(float, __builtin_amdgcn_update_dpp(0, __builtin_bit_cast(int, v), 0x112, 0xf, 0xf, true));
    v += __builtin_bit_cast(float, __builtin_amdgcn_update_dpp(0, __builtin_bit_cast(int, v), 0x114, 0xf, 0xe, true));
    v += __builtin_bit_cast(float, __builtin_amdgcn_update_dpp(0, __builtin_bit_cast(int, v), 0x118, 0xf, 0xc, true));
    v += __builtin_bit_cast(float, __builtin_amdgcn_update_dpp(0, __builtin_bit_cast(int, v), 0x142, 0xa, 0xf, true));
    v += __builtin_bit_cast(float, __builtin_amdgcn_update_dpp(0, __builtin_bit_cast(int, v), 0x143, 0xc, 0xf, true));
    return __builtin_bit_cast(float, __builtin_amdgcn_readlane(__builtin_bit_cast(int, v), 63));
}

__device__ __forceinline__ void cvt8(const uint4 u, float* g) {
    float2 f;
    f = __half22float2(__builtin_bit_cast(__half2, u.x)); g[0] = f.x; g[1] = f.y;
    f = __half22float2(__builtin_bit_cast(__half2, u.y)); g[2] = f.x; g[3] = f.y;
    f = __half22float2(__builtin_bit_cast(__half2, u.z)); g[4] = f.x; g[5] = f.y;
    f = __half22float2(__builtin_bit_cast(__half2, u.w)); g[6] = f.x; g[7] = f.y;
}

// ---------------- Kernel 1: fused [gemm blocks | binA blocks], 32 KB LDS ----------------
// gemm: 64 rows x 64 cols per block, 4 rows/thread, 2-deep x prefetch.
// gcur semantics: offset WITHIN bucket (memset-0 seeded).
__global__ __launch_bounds__(256) void gemm_binA(const float* __restrict__ x,
                                                 const float* __restrict__ W,
                                                 float* __restrict__ h32,
                                                 uint2* __restrict__ h16,
                                                 const int* __restrict__ ei,
                                                 unsigned* __restrict__ gcur,
                                                 unsigned* __restrict__ binned,
                                                 int N, int E, int NB, int ngemm,
                                                 unsigned cap, int mode) {
    __shared__ unsigned smem_u[8192];   // 32 KB shared by both paths

    if ((int)blockIdx.x < ngemm) {
        // ---------- gemm path ----------
        float (*w_lds)[F_OUT] = (float (*)[F_OUT])smem_u;
        {
            const float4* Wv = (const float4*)W;
            float4* wl = (float4*)w_lds;
            for (int i = threadIdx.x; i < F_IN * F_OUT / 4; i += 256) wl[i] = Wv[i];
        }
        __syncthreads();

        const int cg = threadIdx.x & 15;   // 4 cols
        const int rs = threadIdx.x >> 4;   // 16 row slots
        const int row0 = blockIdx.x * 64 + rs * 4;

        int r[4];
#pragma unroll
        for (int i = 0; i < 4; ++i) { const int rr = row0 + i; r[i] = rr < N ? rr : N - 1; }

        float4 acc[4];
#pragma unroll
        for (int i = 0; i < 4; ++i) acc[i] = make_float4(0.f, 0.f, 0.f, 0.f);

        float4 xa[4], xb[4];
#pragma unroll
        for (int i = 0; i < 4; ++i) xa[i] = *(const float4*)(x + (size_t)r[i] * F_IN);
#pragma unroll
        for (int i = 0; i < 4; ++i) xb[i] = *(const float4*)(x + (size_t)r[i] * F_IN + 4);

        for (int k4 = 0; k4 < 32; ++k4) {
            float4 xn[4];
            if (k4 < 30) {
#pragma unroll
                for (int i = 0; i < 4; ++i)
                    xn[i] = *(const float4*)(x + (size_t)r[i] * F_IN + (k4 + 2) * 4);
            }
            float4 wv[4];
#pragma unroll
            for (int kk = 0; kk < 4; ++kk)
                wv[kk] = *(const float4*)&w_lds[k4 * 4 + kk][cg * 4];

#pragma unroll
            for (int i = 0; i < 4; ++i) {
                acc[i].x = fmaf(xa[i].x, wv[0].x, acc[i].x);
                acc[i].y = fmaf(xa[i].x, wv[0].y, acc[i].y);
                acc[i].z = fmaf(xa[i].x, wv[0].z, acc[i].z);
                acc[i].w = fmaf(xa[i].x, wv[0].w, acc[i].w);
                acc[i].x = fmaf(xa[i].y, wv[1].x, acc[i].x);
                acc[i].y = fmaf(xa[i].y, wv[1].y, acc[i].y);
                acc[i].z = fmaf(xa[i].y, wv[1].z, acc[i].z);
                acc[i].w = fmaf(xa[i].y, wv[1].w, acc[i].w);
                acc[i].x = fmaf(xa[i].z, wv[2].x, acc[i].x);
                acc[i].y = fmaf(xa[i].z, wv[2].y, acc[i].y);
                acc[i].z = fmaf(xa[i].z, wv[2].z, acc[i].z);
                acc[i].w = fmaf(xa[i].z, wv[2].w, acc[i].w);
                acc[i].x = fmaf(xa[i].w, wv[3].x, acc[i].x);
                acc[i].y = fmaf(xa[i].w, wv[3].y, acc[i].y);
                acc[i].z = fmaf(xa[i].w, wv[3].z, acc[i].z);
                acc[i].w = fmaf(xa[i].w, wv[3].w, acc[i].w);
            }
#pragma unroll
            for (int i = 0; i < 4; ++i) { xa[i] = xb[i]; }
            if (k4 < 30) {
#pragma unroll
                for (int i = 0; i < 4; ++i) xb[i] = xn[i];
            }
        }

#pragma unroll
        for (int i = 0; i < 4; ++i) {
            const int rr = row0 + i;
            if (rr < N) {
                if (mode & 2) *(float4*)(h32 + (size_t)rr * F_OUT + cg * 4) = acc[i];
                if (mode & 1) {
                    uint2 u;
                    u.x = __builtin_bit_cast(unsigned, __floats2half2_rn(acc[i].x, acc[i].y));
                    u.y = __builtin_bit_cast(unsigned, __floats2half2_rn(acc[i].z, acc[i].w));
                    h16[(size_t)rr * 16 + cg] = u;
                }
            }
        }
    } else {
        // ---------- binA path: 2048 edges/block, bucket-local binning ----------
        unsigned* lcnt  = smem_u;        // [NB]
        unsigned* lbase = smem_u + NB;   // [NB]
        const int t = threadIdx.x;
        for (int i = t; i < NB; i += 256) lcnt[i] = 0;
        __syncthreads();
        const int base = ((int)blockIdx.x - ngemm) * BIN_TILE;
        unsigned pk[8], bk[8], rk[8];
#pragma unroll
        for (int i = 0; i < 8; ++i) {
            const int e = base + i * 256 + t;
            if (e < E) {
                const unsigned s = (unsigned)ei[e];
                const unsigned d = (unsigned)ei[E + e];
                bk[i] = s >> BSHIFT;
                pk[i] = ((s & (BNODES - 1u)) << 17) | d;
                rk[i] = atomicAdd(&lcnt[bk[i]], 1u);
            }
        }
        __syncthreads();
        for (int i = t; i < NB; i += 256) {
            const unsigned c = lcnt[i];
            lbase[i] = c ? atomicAdd(&gcur[i], c) : 0u;   // bucket-local base
        }
        __syncthreads();
#pragma unroll
        for (int i = 0; i < 8; ++i) {
            const int e = base + i * 256 + t;
            if (e < E) {
                const unsigned po = lbase[bk[i]] + rk[i];
                if (po < cap) binned[(size_t)bk[i] * cap + po] = pk[i];
            }
        }
    }
}

// ---------------- Kernel 2: fused binB + node compute, 512 thr, one block per 64-node bucket ----------------
// Single global pass over binned; cross-node + 2-stream chunk pipeline in the node phase.
__global__ __launch_bounds__(512) void bucket_node(const unsigned* __restrict__ binned,
                                                   const unsigned* __restrict__ gcur,
                                                   const uint2* __restrict__ h16v,
                                                   const float* __restrict__ a,
                                                   float* __restrict__ out,
                                                   int N, unsigned cap) {
    __shared__ unsigned raw[BCAP];          // 8 KB: raw (ungrouped) payloads
    __shared__ unsigned stg[BCAP];          // 8 KB: per-node-grouped dst indices
    __shared__ uint4    hsl[BNODES * 8];    // 8 KB: hs rows for this bucket
    __shared__ unsigned ndeg[BNODES];
    __shared__ unsigned nbase[BNODES];
    __shared__ unsigned ncur[BNODES];

    const int b = blockIdx.x;
    const int t = threadIdx.x;
    const int node0 = b << BSHIFT;
    const size_t src0 = (size_t)b * cap;
    unsigned sz = gcur[b]; if (sz > cap) sz = cap;

    if (t < BNODES) ndeg[t] = 0;
    {   // stage this bucket's hs rows (coalesced, 8 KB: one uint4 per thread)
        const uint4* hsrc = (const uint4*)h16v;
        const int limit = N * 8;
        const int gi = node0 * 8 + t;
        hsl[t] = (gi < limit) ? hsrc[gi] : make_uint4(0u, 0u, 0u, 0u);
    }
    for (unsigned i = t; i < sz; i += 512) raw[i] = binned[src0 + i];   // single global pass
    __syncthreads();

    for (unsigned i = t; i < sz; i += 512)
        atomicAdd(&ndeg[raw[i] >> 17], 1u);
    __syncthreads();

    // single-wave inclusive scan over 64 bucket-degrees (threads 0..63 = wave 0)
    if (t < BNODES) {
        const unsigned d = ndeg[t];
        unsigned sc = d;
#pragma unroll
        for (int st = 1; st < BNODES; st <<= 1) {
            const unsigned o = __shfl_up(sc, st, 64);
            if (t >= st) sc += o;
        }
        nbase[t] = sc - d;
        ncur[t]  = sc - d;
    }
    __syncthreads();

    for (unsigned i = t; i < sz; i += 512) {
        const unsigned p = raw[i];
        const unsigned pos = atomicAdd(&ncur[p >> 17], 1u);
        stg[pos] = p & 0x1FFFFu;
    }
    __syncthreads();

    // ---------------- node phase: 16 processors (32 lanes each), 4 nodes each ----------------
    const int lane  = t & 63;
    const int half  = lane >> 5;
    const int slot4 = (lane >> 3) & 3;
    const int q     = lane & 7;
    const int proc  = (t >> 6) * 2 + half;    // 0..15
    const char* h16 = (const char*)h16v;
    const int PN = BNODES / 16;               // 4 nodes per processor

    float b1[8], a2b[8], a3b[8], a0m[8];
#pragma unroll
    for (int f = 0; f < 8; ++f) {
        const float A0 = a[q * 8 + f];
        const float A1 = a[64 + q * 8 + f];
        const float A2 = a[128 + q * 8 + f];
        const float A3 = a[192 + q * 8 + f];
        b1[f]  = fmaf(LK_A, A2 - A3, A1);
        a2b[f] = LK_B * A2;
        a3b[f] = LK_B * A3;
        a0m[f] = fmaf(LK_A, A2 + A3, A0);
    }

    // prime node 0's first-chunk gather
    int begN = (int)nbase[proc * PN];
    int lenN = (int)ndeg[proc * PN];
    int dN = 0;
    if (lenN > 0) { int e0 = slot4; const int lm = lenN - 1; if (e0 > lm) e0 = lm; dN = (int)stg[begN + e0]; }
    uint4 uN = *(const uint4*)(h16 + ((size_t)dN << 7) + q * 16);

#pragma unroll 1
    for (int nn = 0; nn < PN; ++nn) {
        const int nloc = proc * PN + nn;
        const int node = node0 + nloc;
        const int beg = begN;
        const int len = lenN;
        const int lm1 = (len > 0) ? len - 1 : 0;

        uint4 u0 = uN;        // chunk 0 (prefetched during previous node)
        // chunk 4 gather (stream B)
        int dt = 0;
        if (len > 0) { int e1 = 4 + slot4; if (e1 > lm1) e1 = lm1; dt = (int)stg[beg + e1]; }
        uint4 u1 = *(const uint4*)(h16 + ((size_t)dt << 7) + q * 16);
        // chunk 8, 12 indices
        int d2 = 0, d3 = 0;
        if (len > 0) { int e2 = 8 + slot4;  if (e2 > lm1) e2 = lm1; d2 = (int)stg[beg + e2]; }
        if (len > 0) { int e3 = 12 + slot4; if (e3 > lm1) e3 = lm1; d3 = (int)stg[beg + e3]; }

        // issue NEXT node's first-chunk gather before this node's compute
        if (nn + 1 < PN) {
            begN = (int)nbase[nloc + 1];
            lenN = (int)ndeg[nloc + 1];
            int d0 = 0;
            if (lenN > 0) { int e0 = slot4; const int lm = lenN - 1; if (e0 > lm) e0 = lm; d0 = (int)stg[begN + e0]; }
            uN = *(const uint4*)(h16 + ((size_t)d0 << 7) + q * 16);
        }

        float hs[8]; cvt8(hsl[nloc * 8 + q], hs);
        float csp = 0.f;
#pragma unroll
        for (int f = 0; f < 8; ++f) csp = fmaf(hs[f], a0m[f], csp);
        const float cs = sum8(csp);

        float acc[8];
#pragma unroll
        for (int f = 0; f < 8; ++f) acc[f] = 0.f;
        float rsum = 0.f;

        for (int cb = 0; cb < len; cb += 8) {
            // prefetch gathers for chunks cb+8 / cb+12 (guarded to avoid junk traffic)
            uint4 u2 = u1, u3 = u1;
            if (cb + 8 < len)  u2 = *(const uint4*)(h16 + ((size_t)d2 << 7) + q * 16);
            if (cb + 12 < len) u3 = *(const uint4*)(h16 + ((size_t)d3 << 7) + q * 16);
            int d2n = d2, d3n = d3;
            if (cb + 16 < len) { int e = cb + 16 + slot4; if (e > lm1) e = lm1; d2n = (int)stg[beg + e]; }
            if (cb + 20 < len) { int e = cb + 20 + slot4; if (e > lm1) e = lm1; d3n = (int)stg[beg + e]; }

            // ---- stream A: chunk cb ----
            float gA[8]; cvt8(u0, gA);
            float pa0 = 0.f, pa1 = 0.f;
            // ---- stream B: chunk cb+4 ----
            float gB[8]; cvt8(u1, gB);
            float pb0 = 0.f, pb1 = 0.f;
#pragma unroll
            for (int f = 0; f < 8; f += 2) {
                const float saA0 = hs[f] + gA[f],         sbA0 = hs[f] - gA[f];
                const float saA1 = hs[f + 1] + gA[f + 1], sbA1 = hs[f + 1] - gA[f + 1];
                pa0 = fmaf(gA[f],     b1[f],     pa0);
                pa1 = fmaf(gA[f + 1], b1[f + 1], pa1);
                pa0 = fmaf(fabsf(saA0), a2b[f],     pa0);
                pa1 = fmaf(fabsf(saA1), a2b[f + 1], pa1);
                pa0 = fmaf(fabsf(sbA0), a3b[f],     pa0);
                pa1 = fmaf(fabsf(sbA1), a3b[f + 1], pa1);

                const float saB0 = hs[f] + gB[f],         sbB0 = hs[f] - gB[f];
                const float saB1 = hs[f + 1] + gB[f + 1], sbB1 = hs[f + 1] - gB[f + 1];
                pb0 = fmaf(gB[f],     b1[f],     pb0);
                pb1 = fmaf(gB[f + 1], b1[f + 1], pb1);
                pb0 = fmaf(fabsf(saB0), a2b[f],     pb0);
                pb1 = fmaf(fabsf(saB1), a2b[f + 1], pb1);
                pb0 = fmaf(fabsf(sbB0), a3b[f],     pb0);
                pb1 = fmaf(fabsf(sbB1), a3b[f + 1], pb1);
            }
            const float RA = sum8(pa0 + pa1);
            const float RB = sum8(pb0 + pb1);

            float eA = __expf(-leaky(cs + RA));
            float eB = __expf(-leaky(cs + RB));
            eA = (cb + slot4 < len) ? eA : 0.f;
            eB = (cb + 4 + slot4 < len) ? eB : 0.f;
#pragma unroll
            for (int f = 0; f < 8; ++f) {
                acc[f] = fmaf(eA, gA[f], acc[f]);
                acc[f] = fmaf(eB, gB[f], acc[f]);
            }
            rsum += eA + eB;

            u0 = u2; u1 = u3; d2 = d2n; d3 = d3n;
        }

#pragma unroll
        for (int f = 0; f < 8; ++f) acc[f] = xslot_sum2(acc[f]);
        rsum = xslot_sum2(rsum);

        if (slot4 == 0 && node < N) {
            const float inv = 1.f / (rsum + 1e-16f);
            float4 o0, o1;
            o0.x = acc[0] * inv; o0.y = acc[1] * inv; o0.z = acc[2] * inv; o0.w = acc[3] * inv;
            o1.x = acc[4] * inv; o1.y = acc[5] * inv; o1.z = acc[6] * inv; o1.w = acc[7] * inv;
            float* orow = out + (size_t)node * F_OUT + q * 8;
            *(float4*)orow = o0;
            *(float4*)(orow + 4) = o1;
        }
    }
}

// ---------------- Plan B: old CSR build + compact node kernel ----------------
__global__ __launch_bounds__(256) void hist_kernel(const int* __restrict__ ei,
                                                   unsigned* __restrict__ cnt, int E) {
    const int e = blockIdx.x * 256 + threadIdx.x;
    if (e < E) atomicAdd(&cnt[ei[e]], 1u);
}

__global__ __launch_bounds__(256) void scan1(const unsigned* __restrict__ cnt,
                                             unsigned* __restrict__ bsum, int n) {
    __shared__ unsigned lds[256];
    const int t = threadIdx.x;
    const int base = blockIdx.x * 2048 + t * 8;
    unsigned s = 0;
#pragma unroll
    for (int i = 0; i < 8; ++i) { const int idx = base + i; if (idx < n) s += cnt[idx]; }
    lds[t] = s; __syncthreads();
    for (int st = 128; st > 0; st >>= 1) {
        if (t < st) lds[t] += lds[t + st];
        __syncthreads();
    }
    if (t == 0) bsum[blockIdx.x] = lds[0];
}

__global__ __launch_bounds__(128) void scan2(unsigned* __restrict__ bsum,
                                             unsigned* __restrict__ off, int nb, int n) {
    __shared__ unsigned lds[128];
    const int t = threadIdx.x;
    if (t < nb) lds[t] = bsum[t];
    __syncthreads();
    if (t == 0) {
        unsigned run = 0;
        for (int i = 0; i < nb; ++i) { const unsigned v = lds[i]; lds[i] = run; run += v; }
        off[n] = run;
    }
    __syncthreads();
    if (t < nb) bsum[t] = lds[t];
}

__global__ __launch_bounds__(256) void scan3(const unsigned* __restrict__ cnt,
                                             const unsigned* __restrict__ bsum,
                                             unsigned* __restrict__ off,
                                             unsigned* __restrict__ cursor, int n) {
    __shared__ unsigned lds[256];
    const int t = threadIdx.x;
    const int base = blockIdx.x * 2048 + t * 8;
    unsigned v[8]; unsigned s = 0;
#pragma unroll
    for (int i = 0; i < 8; ++i) { const int idx = base + i; v[i] = (idx < n) ? cnt[idx] : 0u; s += v[i]; }
    lds[t] = s; __syncthreads();
    for (int st = 1; st < 256; st <<= 1) {
        const unsigned add = (t >= st) ? lds[t - st] : 0u;
        __syncthreads();
        lds[t] += add;
        __syncthreads();
    }
    unsigned excl = (t > 0 ? lds[t - 1] : 0u) + bsum[blockIdx.x];
#pragma unroll
    for (int i = 0; i < 8; ++i) {
        const int idx = base + i;
        if (idx < n) { off[idx] = excl; cursor[idx] = excl; excl += v[i]; }
    }
}

__global__ __launch_bounds__(256) void scatter_kernel(const int* __restrict__ ei,
                                                      unsigned* __restrict__ cursor,
                                                      int* __restrict__ sdst, int E) {
    const int e = blockIdx.x * 256 + threadIdx.x;
    if (e >= E) return;
    const int s = ei[e];
    const int d = ei[E + e];
    const unsigned pos = atomicAdd(&cursor[s], 1u);
    sdst[pos] = d;
}

__global__ __launch_bounds__(256) void node_kernel(const unsigned* __restrict__ off,
                                                   const unsigned* __restrict__ deg,
                                                   const int* __restrict__ sdst,
                                                   const uint2* __restrict__ h16v,
                                                   const float* __restrict__ a,
                                                   float* __restrict__ out, int N) {
    const int lane  = threadIdx.x & 63;
    const int half  = lane >> 5;
    const int slot4 = (lane >> 3) & 3;
    const int q     = lane & 7;
    const char* h16 = (const char*)h16v;

    float b1[8], a2b[8], a3b[8], a0m[8];
#pragma unroll
    for (int f = 0; f < 8; ++f) {
        const float A0 = a[q * 8 + f];
        const float A1 = a[64 + q * 8 + f];
        const float A2 = a[128 + q * 8 + f];
        const float A3 = a[192 + q * 8 + f];
        b1[f]  = fmaf(LK_A, A2 - A3, A1);
        a2b[f] = LK_B * A2;
        a3b[f] = LK_B * A3;
        a0m[f] = fmaf(LK_A, A2 + A3, A0);
    }

    const int wid = (int)((blockIdx.x * 256u + threadIdx.x) >> 6);
    const int nw  = (int)((gridDim.x * 256u) >> 6);

    for (int pr = wid; pr * 2 < N; pr += nw) {
        const int node = pr * 2 + half;
        const int nc = (node < N) ? node : N - 1;
        const unsigned beg = off[nc];
        const int len = (node < N) ? (int)deg[nc] : 0;

        float hs[8];
        cvt8(*(const uint4*)(h16 + ((size_t)nc << 7) + q * 16), hs);
        float csp = 0.f;
#pragma unroll
        for (int f = 0; f < 8; ++f) csp = fmaf(hs[f], a0m[f], csp);
        const float cs = sum8(csp);

        const int lenO = __shfl_xor(len, 32);
        const int ml = (len > lenO) ? len : lenO;

        float acc[8];
#pragma unroll
        for (int f = 0; f < 8; ++f) acc[f] = 0.f;
        float rsum = 0.f;

        const int lm1 = (len > 0) ? len - 1 : 0;
        int dA = 0;
        if (len > 0) { int e0 = slot4; if (e0 > lm1) e0 = lm1; dA = sdst[beg + e0]; }
        uint4 uA = *(const uint4*)(h16 + ((size_t)dA << 7) + q * 16);
        int dB = dA;
        if (len > 4) { int e1 = 4 + slot4; if (e1 > lm1) e1 = lm1; dB = sdst[beg + e1]; }
        uint4 uB = *(const uint4*)(h16 + ((size_t)dB << 7) + q * 16);
        int dC = dB;
        if (len > 8) { int e2 = 8 + slot4; if (e2 > lm1) e2 = lm1; dC = sdst[beg + e2]; }

        for (int cb = 0; cb < ml; cb += 4) {
            uint4 uC = uB;
            int dD = dC;
            if (cb + 8 < len)
                uC = *(const uint4*)(h16 + ((size_t)dC << 7) + q * 16);
            if (cb + 12 < len) { int e3 = cb + 12 + slot4; if (e3 > lm1) e3 = lm1; dD = sdst[beg + e3]; }

            float g[8];
            cvt8(uA, g);
            float p0 = 0.f, p1 = 0.f;
#pragma unroll
            for (int f = 0; f < 8; f += 2) {
                const float sa0 = hs[f] + g[f],         sb0 = hs[f] - g[f];
                const float sa1 = hs[f + 1] + g[f + 1], sb1 = hs[f + 1] - g[f + 1];
                p0 = fmaf(g[f],     b1[f],     p0);
                p1 = fmaf(g[f + 1], b1[f + 1], p1);
                p0 = fmaf(fabsf(sa0), a2b[f],     p0);
                p1 = fmaf(fabsf(sa1), a2b[f + 1], p1);
                p0 = fmaf(fabsf(sb0), a3b[f],     p0);
                p1 = fmaf(fabsf(sb1), a3b[f + 1], p1);
            }
            const float R = sum8(p0 + p1);
            float e = __expf(-leaky(cs + R));
            e = (cb + slot4 < len) ? e : 0.f;
#pragma unroll
            for (int f = 0; f < 8; ++f) acc[f] = fmaf(e, g[f], acc[f]);
            rsum += e;
            uA = uB; uB = uC; dC = dD;
        }

#pragma unroll
        for (int f = 0; f < 8; ++f) acc[f] = xslot_sum2(acc[f]);
        rsum = xslot_sum2(rsum);

        if (slot4 == 0 && node < N) {
            const float inv = 1.f / (rsum + 1e-16f);
            float4 o0, o1;
            o0.x = acc[0] * inv; o0.y = acc[1] * inv; o0.z = acc[2] * inv; o0.w = acc[3] * inv;
            o1.x = acc[4] * inv; o1.y = acc[5] * inv; o1.z = acc[6] * inv; o1.w = acc[7] * inv;
            float* orow = out + (size_t)node * F_OUT + q * 8;
            *(float4*)orow = o0;
            *(float4*)(orow + 4) = o1;
        }
    }
}

// ---------------- Plan C: atomic fallback ----------------
__device__ __forceinline__ float edge_part(float hs, float hd, float a1, float a2, float a3) {
    float p = hd * a1;
    p = fmaf(leaky(hs + hd), a2, p);
    p = fmaf(leaky(hs - hd), a3, p);
    return p;
}

__global__ __launch_bounds__(256) void edge_kernel(const int* __restrict__ ei,
                                                   const float* __restrict__ h,
                                                   const float* __restrict__ a,
                                                   float* __restrict__ hprime,
                                                   float* __restrict__ rowsum,
                                                   int E) {
    const int lane = threadIdx.x & 63;
    const int wave = (int)((blockIdx.x * blockDim.x + threadIdx.x) >> 6);
    const int nwaves = (int)((gridDim.x * blockDim.x) >> 6);
    const float a0 = a[lane], a1 = a[64 + lane], a2 = a[128 + lane], a3 = a[192 + lane];
    for (int e = wave; e < E; e += nwaves) {
        const int s = ei[e];
        const int d = ei[E + e];
        const float hs = h[(size_t)s * F_OUT + lane];
        const float hd = h[(size_t)d * F_OUT + lane];
        const float part = wave_sum(hs * a0 + edge_part(hs, hd, a1, a2, a3));
        const float ee = __expf(-leaky(part));
        atomicAdd(&hprime[(size_t)s * F_OUT + lane], ee * hd);
        if (lane == 0) atomicAdd(&rowsum[s], ee);
    }
}

__global__ __launch_bounds__(256) void finalize(float* __restrict__ out,
                                                const float* __restrict__ rowsum,
                                                int total) {
    const int i = blockIdx.x * blockDim.x + threadIdx.x;
    if (i < total) out[i] = out[i] / (rowsum[i >> 6] + 1e-16f);
}

static inline size_t align_up(size_t v, size_t a) { return (v + a - 1) & ~(a - 1); }

extern "C" void kernel_launch(void* const* d_in, const int* in_sizes, int n_in,
                              void* d_out, int out_size, void* d_ws, size_t ws_size,
                              hipStream_t stream) {
    const float* x  = (const float*)d_in[0];
    const int*   ei = (const int*)d_in[1];
    const float* W  = (const float*)d_in[2];
    const float* a  = (const float*)d_in[3];

    const int N = in_sizes[0] / F_IN;
    const int E = in_sizes[1] / 2;
    float* out = (float*)d_out;

    const int NB = (N + BNODES - 1) >> BSHIFT;
    const int ngemm = (N + 63) / 64;
    const int nbt = (E + BIN_TILE - 1) / BIN_TILE;
    const unsigned meanFill = (NB > 0) ? (unsigned)(E / NB) : 0u;

    char* ws = (char*)d_ws;
    const size_t szh16  = align_up((size_t)N * F_OUT * 2, 256);
    const size_t szoff  = align_up(((size_t)N + 1) * 4, 256);
    const size_t szedge = align_up((size_t)E * 4 + 64, 256);
    const size_t szbin  = align_up((size_t)NB * BCAP * 4 + 64, 256);

    // plan A: h16 | binned | gcur
    const size_t binned_b = szh16;
    const size_t gcurA_b  = binned_b + szbin;
    const size_t needA    = gcurA_b + align_up((size_t)NB * 4, 256);
    // plan B: h16 | off | deg | sdst | cursor | bsum
    const size_t offB_b   = szh16;
    const size_t degB_b   = offB_b + szoff;
    const size_t sdstB_b  = degB_b + szoff;
    const size_t cursor_b = sdstB_b + szedge;
    const size_t bsum_b   = cursor_b + align_up((size_t)N * 4, 256);
    const size_t needB    = bsum_b + 4096;

    uint2* h16 = (uint2*)ws;

    if (ws_size >= needA && N <= (1 << 17) && NB <= 4096 && meanFill <= (BCAP * 3u) / 4u) {
        unsigned* binned = (unsigned*)(ws + binned_b);
        unsigned* gcur   = (unsigned*)(ws + gcurA_b);

        hipMemsetAsync(gcur, 0, (size_t)NB * 4, stream);
        gemm_binA<<<ngemm + nbt, 256, 0, stream>>>(x, W, nullptr, h16, ei, gcur, binned,
                                                   N, E, NB, ngemm, BCAP, 1);
        bucket_node<<<NB, 512, 0, stream>>>(binned, gcur, h16, a, out, N, BCAP);
    } else if (ws_size >= needB && N <= (1 << 17)) {
        unsigned* off    = (unsigned*)(ws + offB_b);
        unsigned* deg    = (unsigned*)(ws + degB_b);
        int*      sdst   = (int*)(ws + sdstB_b);
        unsigned* cursor = (unsigned*)(ws + cursor_b);
        unsigned* bsum   = (unsigned*)(ws + bsum_b);
        const int nb2 = (N + 2047) / 2048;

        hipMemsetAsync(deg, 0, (size_t)N * 4, stream);
        gemm_binA<<<ngemm, 256, 0, stream>>>(x, W, nullptr, h16, ei, nullptr, nullptr,
                                             N, E, NB, ngemm, BCAP, 1);
        hist_kernel<<<(E + 255) / 256, 256, 0, stream>>>(ei, deg, E);
        scan1<<<nb2, 256, 0, stream>>>(deg, bsum, N);
        scan2<<<1, 128, 0, stream>>>(bsum, off, nb2, N);
        scan3<<<nb2, 256, 0, stream>>>(deg, bsum, off, cursor, N);
        scatter_kernel<<<(E + 255) / 256, 256, 0, stream>>>(ei, cursor, sdst, E);
        node_kernel<<<2048, 256, 0, stream>>>(off, deg, sdst, h16, a, out, N);
    } else {
        float* h32    = (float*)ws;
        float* rowsum = (float*)(ws + align_up((size_t)N * F_OUT * 4, 256));
        hipMemsetAsync(d_out, 0, (size_t)N * F_OUT * sizeof(float), stream);
        hipMemsetAsync(rowsum, 0, (size_t)N * sizeof(float), stream);
        gemm_binA<<<ngemm, 256, 0, stream>>>(x, W, h32, nullptr, ei, nullptr, nullptr,
                                             N, E, NB, ngemm, BCAP, 2);
        edge_kernel<<<2048, 256, 0, stream>>>(ei, h32, a, out, rowsum, E);
        finalize<<<((size_t)N * F_OUT + 255) / 256, 256, 0, stream>>>(out, rowsum, N * F_OUT);
    }
}